// Round 9
// baseline (1572.804 us; speedup 1.0000x reference)
//
#include <hip/hip_runtime.h>
#include <hip/hip_bf16.h>
#include <hip/hip_cooperative_groups.h>

namespace cg = cooperative_groups;

// TransMIL forward. Round 9: revert GEMM to single-buffer 32KB (+XCD swizzle),
// cooperative fused pinv Newton chain (2 launches instead of 24).

#define NT 16385
#define NP 16640
#define PADR 255
#define DIMF 512
#define QKVW 1536
#define NHEAD 8
#define DH 64
#define NLM 256
#define LSEG 65
#define A3V_TC 20

typedef short bf16x8 __attribute__((ext_vector_type(8)));
typedef short bf16x4 __attribute__((ext_vector_type(4)));
typedef float f32x4 __attribute__((ext_vector_type(4)));

__device__ __forceinline__ void gload_lds16(const void* g, void* l) {
    __builtin_amdgcn_global_load_lds(
        (const __attribute__((address_space(1))) void*)g,
        (__attribute__((address_space(3))) void*)l, 16, 0, 0);
}

__device__ __forceinline__ float2 b2f(const __hip_bfloat16* p) {
    ushort2 u = *(const ushort2*)p;
    float2 r;
    r.x = __uint_as_float((unsigned)u.x << 16);
    r.y = __uint_as_float((unsigned)u.y << 16);
    return r;
}

__device__ __forceinline__ unsigned f2b16(float a, float b) {
    union { unsigned u; __hip_bfloat16 h[2]; } c;
    c.h[0] = __float2bfloat16(a); c.h[1] = __float2bfloat16(b);
    return c.u;
}

__device__ __forceinline__ bf16x4 f4b(float a, float b, float c, float d) {
    union { bf16x4 v; __hip_bfloat16 h[4]; } u;
    u.h[0] = __float2bfloat16(a); u.h[1] = __float2bfloat16(b);
    u.h[2] = __float2bfloat16(c); u.h[3] = __float2bfloat16(d);
    return u.v;
}

// ---------------- bf16 MFMA GEMM (single-buffer 32KB LDS + bijective XCD swizzle)
// C = A[MxK]@BT[NxK]^T + bias (+Cacc)(+relu); fp32 C or bf16 C16.
__global__ __launch_bounds__(256) void gemm_bf16_k(
    const __hip_bfloat16* __restrict__ A, const __hip_bfloat16* __restrict__ BT,
    const float* __restrict__ bias, const float* __restrict__ Cacc,
    float* __restrict__ C, __hip_bfloat16* __restrict__ C16,
    int M, int N, int K, int MA, int relu)
{
    __shared__ __align__(16) __hip_bfloat16 Asl[128 * 64];
    __shared__ __align__(16) __hip_bfloat16 Bsl[128 * 64];
    int tid = threadIdx.x;
    int wid = tid >> 6, lane = tid & 63;
    // bijective XCD-chunked swizzle (m204)
    int nwg = (int)(gridDim.x * gridDim.y);
    int orig = (int)(blockIdx.y * gridDim.x + blockIdx.x);
    int qq = nwg >> 3, rr = nwg & 7;
    int xcd = orig & 7, idx = orig >> 3;
    int wg = (xcd < rr ? xcd * (qq + 1) : rr * (qq + 1) + (xcd - rr) * qq) + idx;
    int m0 = (wg / (int)gridDim.x) << 7, n0 = (wg % (int)gridDim.x) << 7;
    int wr = (wid >> 1) << 6, wc = (wid & 1) << 6;
    f32x4 acc[4][4] = {};
    int lr = lane >> 3, lk = (lane & 7) << 3;
    for (int kt = 0; kt < K; kt += 64) {
#pragma unroll
        for (int i = 0; i < 4; ++i) {
            int ch = wid * 4 + i;
            int rowA = m0 + ch * 8 + lr;
            rowA = rowA < MA ? rowA : (MA - 1);
            gload_lds16(A + (size_t)rowA * K + kt + lk, &Asl[ch * 512]);
            int rowB = n0 + ch * 8 + lr;
            gload_lds16(BT + (size_t)rowB * K + kt + lk, &Bsl[ch * 512]);
        }
        __syncthreads();
#pragma unroll
        for (int ks = 0; ks < 2; ++ks) {
            int kb = ks * 32 + (lane >> 4) * 8;
            bf16x8 af[4], bfr[4];
#pragma unroll
            for (int m = 0; m < 4; ++m)
                af[m] = *(const bf16x8*)&Asl[(wr + m * 16 + (lane & 15)) * 64 + kb];
#pragma unroll
            for (int n = 0; n < 4; ++n)
                bfr[n] = *(const bf16x8*)&Bsl[(wc + n * 16 + (lane & 15)) * 64 + kb];
#pragma unroll
            for (int m = 0; m < 4; ++m)
#pragma unroll
                for (int n = 0; n < 4; ++n)
                    acc[m][n] = __builtin_amdgcn_mfma_f32_16x16x32_bf16(
                        af[m], bfr[n], acc[m][n], 0, 0, 0);
        }
        __syncthreads();
    }
    int cr = (lane >> 4) << 2, cc = lane & 15;
#pragma unroll
    for (int m = 0; m < 4; ++m) {
#pragma unroll
        for (int i = 0; i < 4; ++i) {
            int gm = m0 + wr + m * 16 + cr + i;
            if (gm >= M) continue;
#pragma unroll
            for (int n = 0; n < 4; ++n) {
                int gn = n0 + wc + n * 16 + cc;
                float v = acc[m][n][i];
                if (bias) v += bias[gn];
                if (Cacc) v += Cacc[(size_t)gm * N + gn];
                if (relu) v = fmaxf(v, 0.f);
                if (C16) C16[(size_t)gm * N + gn] = __float2bfloat16(v);
                else C[(size_t)gm * N + gn] = v;
            }
        }
    }
}

// ---------------- fp32 [KxN] -> bf16 [NxK] tiled transpose-convert
__global__ __launch_bounds__(256) void transcvt_k(const float* __restrict__ W,
    __hip_bfloat16* __restrict__ WT, int K, int N)
{
    __shared__ float t[32][33];
    int nt = N >> 5;
    int n0 = (blockIdx.x % nt) << 5, k0 = (blockIdx.x / nt) << 5;
    int tx = threadIdx.x & 31, ty = threadIdx.x >> 5;
    for (int r = ty; r < 32; r += 8) t[r][tx] = W[(size_t)(k0 + r) * N + n0 + tx];
    __syncthreads();
    for (int r = ty; r < 32; r += 8)
        WT[(size_t)(n0 + r) * K + k0 + tx] = __float2bfloat16(t[tx][r]);
}

// ---------------- fp32 -> bf16 convert (vectorized)
__global__ __launch_bounds__(256) void cvt_k(const float4* __restrict__ in,
    ushort4* __restrict__ out, int n4)
{
    int i = blockIdx.x * 256 + threadIdx.x;
    if (i >= n4) return;
    float4 v = in[i];
    union { __hip_bfloat16 h[4]; ushort4 u; } cv;
    cv.h[0] = __float2bfloat16(v.x); cv.h[1] = __float2bfloat16(v.y);
    cv.h[2] = __float2bfloat16(v.z); cv.h[3] = __float2bfloat16(v.w);
    out[i] = cv.u;
}

// ---------------- v transpose: vT16[h][d][t]
__global__ __launch_bounds__(256) void vtrans_k(const __hip_bfloat16* __restrict__ qkvb16,
    __hip_bfloat16* __restrict__ vT16)
{
    int h = blockIdx.y;
    int t0 = blockIdx.x << 6;
    __shared__ float tile[64][65];
    int tid = threadIdx.x;
    for (int e = tid; e < 512; e += 256) {
        int r = e >> 3, c8 = (e & 7) << 3;
        union { bf16x8 v; __hip_bfloat16 hh[8]; } u;
        u.v = *(const bf16x8*)(qkvb16 + (size_t)(t0 + r) * QKVW + 1024 + (h << 6) + c8);
#pragma unroll
        for (int j = 0; j < 8; ++j) tile[r][c8 + j] = __bfloat162float(u.hh[j]);
    }
    __syncthreads();
    for (int e = tid; e < 512; e += 256) {
        int d = e >> 3, t8 = (e & 7) << 3;
        union { bf16x8 v; __hip_bfloat16 hh[8]; } u;
#pragma unroll
        for (int j = 0; j < 8; ++j) u.hh[j] = __float2bfloat16(tile[t8 + j][d]);
        *(bf16x8*)(vT16 + ((size_t)(h << 6) + d) * NP + t0 + t8) = u.v;
    }
}

// ---------------- LayerNorm per row (512) -> bf16 out
__global__ __launch_bounds__(64) void ln_k(const float* __restrict__ in,
    const float* __restrict__ g, const float* __restrict__ b,
    __hip_bfloat16* __restrict__ out, int rows)
{
    int r = blockIdx.x;
    if (r >= rows) return;
    int lane = threadIdx.x;
    const float* xr = in + (size_t)r * DIMF;
    float v[8], s = 0.f;
#pragma unroll
    for (int i = 0; i < 8; ++i) { v[i] = xr[i * 64 + lane]; s += v[i]; }
#pragma unroll
    for (int off = 32; off; off >>= 1) s += __shfl_xor(s, off);
    float mu = s * (1.f / 512.f);
    float vs = 0.f;
#pragma unroll
    for (int i = 0; i < 8; ++i) { float d = v[i] - mu; vs += d * d; }
#pragma unroll
    for (int off = 32; off; off >>= 1) vs += __shfl_xor(vs, off);
    float rstd = rsqrtf(vs * (1.f / 512.f) + 1e-5f);
    __hip_bfloat16* orow = out + (size_t)r * DIMF;
#pragma unroll
    for (int i = 0; i < 8; ++i) {
        int d = i * 64 + lane;
        orow[d] = __float2bfloat16((v[i] - mu) * rstd * g[d] + b[d]);
    }
}

// ---------------- landmark means, 4 waves split the 65-row sum
__global__ __launch_bounds__(256) void landmark_k(const __hip_bfloat16* __restrict__ qkvb16,
    float* __restrict__ ql, float* __restrict__ kl,
    __hip_bfloat16* __restrict__ ql16, __hip_bfloat16* __restrict__ kl16)
{
    int bx = blockIdx.x;
    int h = bx >> 8, j = bx & 255;
    int w = threadIdx.x >> 6, d = threadIdx.x & 63;
    __shared__ float pq[4][64], pk[4][64];
    float qs = 0.f, ks = 0.f;
    for (int u = w; u < LSEG; u += 4) {
        size_t addr = (size_t)(j * LSEG + u) * QKVW + (h << 6) + d;
        qs += __bfloat162float(qkvb16[addr]);
        ks += __bfloat162float(qkvb16[addr + 512]);
    }
    pq[w][d] = qs; pk[w][d] = ks;
    __syncthreads();
    if (threadIdx.x < 64) {
        float q = pq[0][d] + pq[1][d] + pq[2][d] + pq[3][d];
        float k = pk[0][d] + pk[1][d] + pk[2][d] + pk[3][d];
        float qm = q * (1.f / 65.f) * 0.125f;
        float km = k * (1.f / 65.f);
        ql[(size_t)bx * 64 + d] = qm;
        kl[(size_t)bx * 64 + d] = km;
        ql16[(size_t)bx * 64 + d] = __float2bfloat16(qm);
        kl16[(size_t)bx * 64 + d] = __float2bfloat16(km);
    }
}

// ---------------- a2 = softmax(q_l @ k_l^T); writes fp32 + bf16 row-major
__global__ __launch_bounds__(256) void a2_k(const float* __restrict__ ql,
    const float* __restrict__ kl, float* __restrict__ a2, __hip_bfloat16* __restrict__ a2_16)
{
    int h = blockIdx.x >> 8, i = blockIdx.x & 255;
    int j = threadIdx.x;
    __shared__ float qs[64];
    __shared__ float red[256];
    if (j < 64) qs[j] = ql[((size_t)(h << 8) + i) * 64 + j];
    __syncthreads();
    const float* kr = kl + ((size_t)(h << 8) + j) * 64;
    float s = 0.f;
#pragma unroll 8
    for (int d = 0; d < 64; ++d) s += qs[d] * kr[d];
    red[j] = s; __syncthreads();
    for (int st = 128; st; st >>= 1) { if (j < st) red[j] = fmaxf(red[j], red[j + st]); __syncthreads(); }
    float mx = red[0]; __syncthreads();
    float p = __expf(s - mx);
    red[j] = p; __syncthreads();
    for (int st = 128; st; st >>= 1) { if (j < st) red[j] += red[j + st]; __syncthreads(); }
    float v = p / red[0];
    a2[((size_t)h << 16) + i * 256 + j] = v;
    a2_16[((size_t)h << 16) + i * 256 + j] = __float2bfloat16(v);
}

// ---------------- pinv init: z = a2^T/(maxrow*maxcol); LDS-tiled transpose
__global__ __launch_bounds__(256) void zinit_k(const float* __restrict__ a2,
    __hip_bfloat16* __restrict__ zr16, __hip_bfloat16* __restrict__ zT16)
{
    int h = blockIdx.x, t = threadIdx.x;
    const float* X = a2 + ((size_t)h << 16);
    __shared__ float red[256];
    __shared__ float tl[64][65];
    float rs = 0.f;
    const float4* Xr = (const float4*)(X + (size_t)t * 256);
    for (int j = 0; j < 64; ++j) {
        float4 v = Xr[j];
        rs += fabsf(v.x) + fabsf(v.y) + fabsf(v.z) + fabsf(v.w);
    }
    red[t] = rs; __syncthreads();
    for (int st = 128; st; st >>= 1) { if (t < st) red[t] = fmaxf(red[t], red[t + st]); __syncthreads(); }
    float colv = red[0]; __syncthreads();
    float cs = 0.f;
    for (int i = 0; i < 256; ++i) cs += fabsf(X[i * 256 + t]);
    red[t] = cs; __syncthreads();
    for (int st = 128; st; st >>= 1) { if (t < st) red[t] = fmaxf(red[t], red[t + st]); __syncthreads(); }
    float rowv = red[0];
    float inv = 1.f / (colv * rowv);
    int cl = t & 63, rg = t >> 6;
    for (int tr = 0; tr < 4; ++tr)
        for (int tc = 0; tc < 4; ++tc) {
            __syncthreads();
#pragma unroll
            for (int k = 0; k < 16; ++k) {
                int rl = (k << 2) + rg;
                tl[rl][cl] = X[(size_t)(tr * 64 + rl) * 256 + tc * 64 + cl];
            }
            __syncthreads();
#pragma unroll
            for (int k = 0; k < 16; ++k) {
                int rl = (k << 2) + rg;
                zT16[((size_t)h << 16) + (size_t)(tr * 64 + rl) * 256 + tc * 64 + cl] =
                    __float2bfloat16(tl[rl][cl] * inv);
                zr16[((size_t)h << 16) + (size_t)(tc * 64 + rl) * 256 + tr * 64 + cl] =
                    __float2bfloat16(tl[cl][rl] * inv);
            }
        }
}

// ---------------- cooperative fused pinv Newton chain: 6 iterations in one
// launch. Grid = 32 blocks (4 col-stripes x 8 heads), 256 thr. Per iteration:
// G1 (xz = a2@Z, + t1T = 7I - xz^T) -> grid.sync -> G2,G3,G4 fused per stripe
// (ta=15I-xz@t1 -> tb=13I-xz@ta -> Zn=0.25*Z@tb) -> grid.sync -> swap.
__global__ __launch_bounds__(256) void pinv_coop_k(
    const __hip_bfloat16* __restrict__ a2_16,
    __hip_bfloat16* zr0, __hip_bfloat16* zr1,
    __hip_bfloat16* zt0, __hip_bfloat16* zt1,
    __hip_bfloat16* __restrict__ xz16, __hip_bfloat16* __restrict__ t1T16)
{
    __shared__ __align__(16) __hip_bfloat16 tA[64][264];
    __shared__ __align__(16) __hip_bfloat16 tB[64][264];
    cg::grid_group gg = cg::this_grid();
    int bid = (int)blockIdx.x;
    int h = bid >> 2, n0 = (bid & 3) << 6;
    int lane = threadIdx.x & 63;
    int r0 = (threadIdx.x >> 6) << 6;
    int rA = lane & 15, g = lane >> 4, kp = g << 3;
    const __hip_bfloat16* Ah = a2_16 + ((size_t)h << 16);
    __hip_bfloat16* xzh = xz16 + ((size_t)h << 16);
    __hip_bfloat16* t1h = t1T16 + ((size_t)h << 16);
    __hip_bfloat16* zr = zr0; __hip_bfloat16* zt = zt0;
    __hip_bfloat16* zrN = zr1; __hip_bfloat16* ztN = zt1;
    for (int it = 0; it < 6; ++it) {
        // ---- G1: xz stripe = a2 @ Z[:, stripe]  (B-frags from zt rows)
        {
            const __hip_bfloat16* Bh = zt + ((size_t)h << 16);
            f32x4 acc[4][4] = {};
            for (int ks = 0; ks < 8; ++ks) {
                bf16x8 af[4], bfr[4];
#pragma unroll
                for (int m = 0; m < 4; ++m)
                    af[m] = *(const bf16x8*)&Ah[(size_t)(r0 + m * 16 + rA) * 256 + ks * 32 + kp];
#pragma unroll
                for (int n = 0; n < 4; ++n)
                    bfr[n] = *(const bf16x8*)&Bh[(size_t)(n0 + n * 16 + rA) * 256 + ks * 32 + kp];
#pragma unroll
                for (int m = 0; m < 4; ++m)
#pragma unroll
                    for (int n = 0; n < 4; ++n)
                        acc[m][n] = __builtin_amdgcn_mfma_f32_16x16x32_bf16(af[m], bfr[n], acc[m][n], 0, 0, 0);
            }
#pragma unroll
            for (int m = 0; m < 4; ++m)
#pragma unroll
                for (int i = 0; i < 4; ++i) {
                    int gr = r0 + m * 16 + (g << 2) + i;
#pragma unroll
                    for (int n = 0; n < 4; ++n) {
                        int gc = n0 + n * 16 + rA;
                        float v = acc[m][n][i];
                        xzh[(size_t)gr * 256 + gc] = __float2bfloat16(v);
                        t1h[(size_t)gc * 256 + gr] = __float2bfloat16((gr == gc ? 7.f : 0.f) - v);
                    }
                }
        }
        gg.sync();
        // ---- G2: tA = (15I - xz @ t1)[:, stripe]  (stored transposed in LDS)
        {
            f32x4 acc[4][4] = {};
            for (int ks = 0; ks < 8; ++ks) {
                bf16x8 af[4], bfr[4];
#pragma unroll
                for (int m = 0; m < 4; ++m)
                    af[m] = *(const bf16x8*)&xzh[(size_t)(r0 + m * 16 + rA) * 256 + ks * 32 + kp];
#pragma unroll
                for (int n = 0; n < 4; ++n)
                    bfr[n] = *(const bf16x8*)&t1h[(size_t)(n0 + n * 16 + rA) * 256 + ks * 32 + kp];
#pragma unroll
                for (int m = 0; m < 4; ++m)
#pragma unroll
                    for (int n = 0; n < 4; ++n)
                        acc[m][n] = __builtin_amdgcn_mfma_f32_16x16x32_bf16(af[m], bfr[n], acc[m][n], 0, 0, 0);
            }
#pragma unroll
            for (int m = 0; m < 4; ++m)
#pragma unroll
                for (int n = 0; n < 4; ++n) {
                    int gr0 = r0 + m * 16 + (g << 2);
                    int cl = n * 16 + rA;
                    *(bf16x4*)&tA[cl][gr0] = f4b(
                        ((gr0 + 0 == n0 + cl) ? 15.f : 0.f) - acc[m][n][0],
                        ((gr0 + 1 == n0 + cl) ? 15.f : 0.f) - acc[m][n][1],
                        ((gr0 + 2 == n0 + cl) ? 15.f : 0.f) - acc[m][n][2],
                        ((gr0 + 3 == n0 + cl) ? 15.f : 0.f) - acc[m][n][3]);
                }
        }
        __syncthreads();
        // ---- G3: tB = (13I - xz @ tA)[:, stripe]
        {
            f32x4 acc[4][4] = {};
            for (int ks = 0; ks < 8; ++ks) {
                bf16x8 af[4], bfr[4];
#pragma unroll
                for (int m = 0; m < 4; ++m)
                    af[m] = *(const bf16x8*)&xzh[(size_t)(r0 + m * 16 + rA) * 256 + ks * 32 + kp];
#pragma unroll
                for (int n = 0; n < 4; ++n)
                    bfr[n] = *(const bf16x8*)&tA[n * 16 + rA][ks * 32 + kp];
#pragma unroll
                for (int m = 0; m < 4; ++m)
#pragma unroll
                    for (int n = 0; n < 4; ++n)
                        acc[m][n] = __builtin_amdgcn_mfma_f32_16x16x32_bf16(af[m], bfr[n], acc[m][n], 0, 0, 0);
            }
#pragma unroll
            for (int m = 0; m < 4; ++m)
#pragma unroll
                for (int n = 0; n < 4; ++n) {
                    int gr0 = r0 + m * 16 + (g << 2);
                    int cl = n * 16 + rA;
                    *(bf16x4*)&tB[cl][gr0] = f4b(
                        ((gr0 + 0 == n0 + cl) ? 13.f : 0.f) - acc[m][n][0],
                        ((gr0 + 1 == n0 + cl) ? 13.f : 0.f) - acc[m][n][1],
                        ((gr0 + 2 == n0 + cl) ? 13.f : 0.f) - acc[m][n][2],
                        ((gr0 + 3 == n0 + cl) ? 13.f : 0.f) - acc[m][n][3]);
                }
        }
        __syncthreads();
        // ---- G4: Zn[:, stripe] = 0.25 * Z @ tB
        {
            const __hip_bfloat16* Zh = zr + ((size_t)h << 16);
            f32x4 acc[4][4] = {};
            for (int ks = 0; ks < 8; ++ks) {
                bf16x8 af[4], bfr[4];
#pragma unroll
                for (int m = 0; m < 4; ++m)
                    af[m] = *(const bf16x8*)&Zh[(size_t)(r0 + m * 16 + rA) * 256 + ks * 32 + kp];
#pragma unroll
                for (int n = 0; n < 4; ++n)
                    bfr[n] = *(const bf16x8*)&tB[n * 16 + rA][ks * 32 + kp];
#pragma unroll
                for (int m = 0; m < 4; ++m)
#pragma unroll
                    for (int n = 0; n < 4; ++n)
                        acc[m][n] = __builtin_amdgcn_mfma_f32_16x16x32_bf16(af[m], bfr[n], acc[m][n], 0, 0, 0);
            }
            __hip_bfloat16* zrh = zrN + ((size_t)h << 16);
            __hip_bfloat16* zth = ztN + ((size_t)h << 16);
#pragma unroll
            for (int m = 0; m < 4; ++m)
#pragma unroll
                for (int i = 0; i < 4; ++i) {
                    int gr = r0 + m * 16 + (g << 2) + i;
#pragma unroll
                    for (int n = 0; n < 4; ++n) {
                        int gc = n0 + n * 16 + rA;
                        float v = 0.25f * acc[m][n][i];
                        zrh[(size_t)gr * 256 + gc] = __float2bfloat16(v);
                        zth[(size_t)gc * 256 + gr] = __float2bfloat16(v);
                    }
                }
        }
        gg.sync();
        __hip_bfloat16* t;
        t = zr; zr = zrN; zrN = t;
        t = zt; zt = ztN; ztN = t;
    }
}

// ---------------- wm = Zfinal @ a3v -> wmT16
__global__ __launch_bounds__(256) void wm_k(
    const __hip_bfloat16* __restrict__ zr16, const __hip_bfloat16* __restrict__ a3vT16,
    __hip_bfloat16* __restrict__ wmT16)
{
    int h = blockIdx.x;
    int lane = threadIdx.x & 63;
    int r0 = (threadIdx.x >> 6) << 6;
    int rA = lane & 15, g = lane >> 4, kp = g << 3;
    const __hip_bfloat16* Zh = zr16 + ((size_t)h << 16);
    const __hip_bfloat16* Bh = a3vT16 + ((size_t)h << 14);
    f32x4 acc[4][4] = {};
    for (int ks = 0; ks < 8; ++ks) {
        bf16x8 af[4], bfr[4];
#pragma unroll
        for (int m = 0; m < 4; ++m)
            af[m] = *(const bf16x8*)&Zh[(size_t)(r0 + m * 16 + rA) * 256 + ks * 32 + kp];
#pragma unroll
        for (int n = 0; n < 4; ++n)
            bfr[n] = *(const bf16x8*)&Bh[(size_t)(n * 16 + rA) * 256 + ks * 32 + kp];
#pragma unroll
        for (int m = 0; m < 4; ++m)
#pragma unroll
            for (int n = 0; n < 4; ++n)
                acc[m][n] = __builtin_amdgcn_mfma_f32_16x16x32_bf16(af[m], bfr[n], acc[m][n], 0, 0, 0);
    }
    __hip_bfloat16* Wh = wmT16 + ((size_t)h << 14);
#pragma unroll
    for (int m = 0; m < 4; ++m)
#pragma unroll
        for (int i = 0; i < 4; ++i) {
            int gr = r0 + m * 16 + (g << 2) + i;
#pragma unroll
            for (int n = 0; n < 4; ++n)
                Wh[(size_t)(n * 16 + rA) * 256 + gr] = __float2bfloat16(acc[m][n][i]);
        }
}

// ---------------- MFMA flash a3v partials
__global__ __launch_bounds__(128) void a3v_flash_k(
    const __hip_bfloat16* __restrict__ ql16, const __hip_bfloat16* __restrict__ qkvb16,
    const __hip_bfloat16* __restrict__ vT16,
    float* __restrict__ opart, float* __restrict__ mpart, float* __restrict__ lpart)
{
    int bx = blockIdx.x;
    int h = bx >> 2, qb = bx & 3;
    int tc = blockIdx.y;
    int wv = threadIdx.x >> 6;
    int lane = threadIdx.x & 63;
    int rA = lane & 15, g = lane >> 4, kp = g << 3;
    __shared__ __align__(16) __hip_bfloat16 Plds[2][32 * 64];
    char* P = (char*)&Plds[wv][0];

    bf16x8 qa[2][2];
    const __hip_bfloat16* qlh = ql16 + ((size_t)h << 14);
#pragma unroll
    for (int m = 0; m < 2; ++m)
#pragma unroll
        for (int ks = 0; ks < 2; ++ks)
            qa[m][ks] = *(const bf16x8*)(qlh +
                (size_t)((qb << 6) + (wv << 5) + (m << 4) + rA) * 64 + ks * 32 + kp);

    const __hip_bfloat16* kg = qkvb16 + 512 + (h << 6);
    const __hip_bfloat16* vg = vT16 + ((size_t)(h << 6)) * NP;

    f32x4 O[2][4] = {};
    float m_[2][4], l_[2][4];
#pragma unroll
    for (int m = 0; m < 2; ++m)
#pragma unroll
        for (int i = 0; i < 4; ++i) { m_[m][i] = -3e38f; l_[m][i] = 0.f; }

    for (int tile = tc * 13; tile < tc * 13 + 13; ++tile) {
        int t0 = tile << 6;
        f32x4 S[2][4] = {};
#pragma unroll
        for (int n = 0; n < 4; ++n)
#pragma unroll
            for (int ks = 0; ks < 2; ++ks) {
                bf16x8 kb = *(const bf16x8*)(kg + (size_t)(t0 + (n << 4) + rA) * QKVW + ks * 32 + kp);
                S[0][n] = __builtin_amdgcn_mfma_f32_16x16x32_bf16(qa[0][ks], kb, S[0][n], 0, 0, 0);
                S[1][n] = __builtin_amdgcn_mfma_f32_16x16x32_bf16(qa[1][ks], kb, S[1][n], 0, 0, 0);
            }
        float f_[2][4];
#pragma unroll
        for (int m = 0; m < 2; ++m)
#pragma unroll
            for (int i = 0; i < 4; ++i) {
                float mx = fmaxf(fmaxf(S[m][0][i], S[m][1][i]), fmaxf(S[m][2][i], S[m][3][i]));
#pragma unroll
                for (int msk = 8; msk; msk >>= 1) mx = fmaxf(mx, __shfl_xor(mx, msk));
                float mn = fmaxf(m_[m][i], mx);
                float f = __expf(m_[m][i] - mn);
                int r = (m << 4) + (g << 2) + i;
                int swz = (r & 7) << 4;
                float sum = 0.f;
#pragma unroll
                for (int n = 0; n < 4; ++n) {
                    float p = __expf(S[m][n][i] - mn);
                    sum += p;
                    int byte = (r << 7) + (((n << 4) + rA) << 1);
                    *(__hip_bfloat16*)(P + (byte ^ swz)) = __float2bfloat16(p);
                }
#pragma unroll
                for (int msk = 8; msk; msk >>= 1) sum += __shfl_xor(sum, msk);
                l_[m][i] = l_[m][i] * f + sum;
                m_[m][i] = mn;
                f_[m][i] = f;
            }
#pragma unroll
        for (int m = 0; m < 2; ++m)
#pragma unroll
            for (int i = 0; i < 4; ++i) {
                float f = f_[m][i];
#pragma unroll
                for (int n = 0; n < 4; ++n) O[m][n][i] *= f;
            }
#pragma unroll
        for (int ks2 = 0; ks2 < 2; ++ks2) {
            bf16x8 pa[2];
#pragma unroll
            for (int m = 0; m < 2; ++m) {
                int rr = (m << 4) + rA;
                int byte = (rr << 7) + ((ks2 * 32 + kp) << 1);
                pa[m] = *(const bf16x8*)(P + (byte ^ ((rr & 7) << 4)));
            }
#pragma unroll
            for (int n = 0; n < 4; ++n) {
                bf16x8 vb = *(const bf16x8*)(vg + (size_t)((n << 4) + rA) * NP + t0 + ks2 * 32 + kp);
                O[0][n] = __builtin_amdgcn_mfma_f32_16x16x32_bf16(pa[0], vb, O[0][n], 0, 0, 0);
                O[1][n] = __builtin_amdgcn_mfma_f32_16x16x32_bf16(pa[1], vb, O[1][n], 0, 0, 0);
            }
        }
    }
    int pb2 = (bx << 1) | wv;
    size_t obase = ((size_t)pb2 * A3V_TC + tc) * 2048;
#pragma unroll
    for (int m = 0; m < 2; ++m)
#pragma unroll
        for (int i = 0; i < 4; ++i) {
            int r = (m << 4) + (g << 2) + i;
#pragma unroll
            for (int n = 0; n < 4; ++n)
                opart[obase + (size_t)r * 64 + (n << 4) + rA] = O[m][n][i];
            if (rA == 0) {
                mpart[((size_t)pb2 * A3V_TC + tc) * 32 + r] = m_[m][i];
                lpart[((size_t)pb2 * A3V_TC + tc) * 32 + r] = l_[m][i];
            }
        }
}

// ---------------- a3v combine -> a3vT16[h][d][j] bf16
__global__ __launch_bounds__(64) void a3v_comb_k(const float* __restrict__ opart,
    const float* __restrict__ mpart, const float* __restrict__ lpart,
    __hip_bfloat16* __restrict__ a3vT16)
{
    int pb = blockIdx.x, d = threadIdx.x;
    int h = pb >> 3;
    for (int r = 0; r < 32; ++r) {
        float M = -3e38f;
        for (int tc = 0; tc < A3V_TC; ++tc)
            M = fmaxf(M, mpart[((size_t)pb * A3V_TC + tc) * 32 + r]);
        float L = 0.f, od = 0.f;
        for (int tc = 0; tc < A3V_TC; ++tc) {
            float w = __expf(mpart[((size_t)pb * A3V_TC + tc) * 32 + r] - M);
            L += lpart[((size_t)pb * A3V_TC + tc) * 32 + r] * w;
            od += w * opart[((size_t)pb * A3V_TC + tc) * 2048 + (size_t)r * 64 + d];
        }
        int j = ((pb & 7) << 5) + r;
        a3vT16[((size_t)((h << 6) + d) << 8) + j] = __float2bfloat16(od / L);
    }
}

// ---------------- MFMA fused sim1-softmax @ Wm -> bf16 out
__global__ __launch_bounds__(128) void attnout_mfma_k(
    const __hip_bfloat16* __restrict__ qkvb16, const __hip_bfloat16* __restrict__ kl16,
    const __hip_bfloat16* __restrict__ wmT16, __hip_bfloat16* __restrict__ o)
{
    int h = blockIdx.y;
    int rbase = (blockIdx.x << 6) + ((threadIdx.x >> 6) << 5);
    int lane = threadIdx.x & 63;
    int rA = lane & 15;
    int g = lane >> 4;
    int kp = g << 3;
    __shared__ __align__(16) __hip_bfloat16 Plds[2][32 * 256];
    char* P = (char*)&Plds[threadIdx.x >> 6][0];

    bf16x8 qa[2][2];
#pragma unroll
    for (int m = 0; m < 2; ++m)
#pragma unroll
        for (int ks = 0; ks < 2; ++ks)
            qa[m][ks] = *(const bf16x8*)(qkvb16 +
                (size_t)(rbase + m * 16 + rA) * QKVW + (h << 6) + ks * 32 + kp);

    const __hip_bfloat16* klh = kl16 + ((size_t)h << 14);
    f32x4 S[2][16] = {};
#pragma unroll
    for (int n = 0; n < 16; ++n) {
#pragma unroll
        for (int ks = 0; ks < 2; ++ks) {
            bf16x8 kb = *(const bf16x8*)(klh + (size_t)((n << 4) + rA) * 64 + ks * 32 + kp);
            S[0][n] = __builtin_amdgcn_mfma_f32_16x16x32_bf16(qa[0][ks], kb, S[0][n], 0, 0, 0);
            S[1][n] = __builtin_amdgcn_mfma_f32_16x16x32_bf16(qa[1][ks], kb, S[1][n], 0, 0, 0);
        }
    }
#pragma unroll
    for (int m = 0; m < 2; ++m)
#pragma unroll
        for (int n = 0; n < 16; ++n) S[m][n] *= 0.125f;

    float lsum[2][4];
#pragma unroll
    for (int m = 0; m < 2; ++m)
#pragma unroll
        for (int i = 0; i < 4; ++i) {
            float mx = -3e38f;
#pragma unroll
            for (int n = 0; n < 16; ++n) mx = fmaxf(mx, S[m][n][i]);
#pragma unroll
            for (int msk = 8; msk; msk >>= 1) mx = fmaxf(mx, __shfl_xor(mx, msk));
            float sum = 0.f;
            int r = (m << 4) + (g << 2) + i;
            int swz = (r & 7) << 4;
#pragma unroll
            for (int n = 0; n < 16; ++n) {
                float p = __expf(S[m][n][i] - mx);
                sum += p;
                int byte = (r << 9) + (((n << 4) + rA) << 1);
                *(__hip_bfloat16*)(P + (byte ^ swz)) = __float2bfloat16(p);
            }
#pragma unroll
            for (int msk = 8; msk; msk >>= 1) sum += __shfl_xor(sum, msk);
            lsum[m][i] = sum;
        }

    const __hip_bfloat16* wmh = wmT16 + ((size_t)h << 14);
    f32x4 O[2][4] = {};
#pragma unroll
    for (int kc = 0; kc < 8; ++kc) {
        bf16x8 pa[2];
#pragma unroll
        for (int m = 0; m < 2; ++m) {
            int rr = (m << 4) + rA;
            int byte = (rr << 9) + (((kc << 5) + kp) << 1);
            pa[m] = *(const bf16x8*)(P + (byte ^ ((rr & 7) << 4)));
        }
#pragma unroll
        for (int n = 0; n < 4; ++n) {
            bf16x8 wb = *(const bf16x8*)(wmh + (size_t)((n << 4) + rA) * 256 + (kc << 5) + kp);
#pragma unroll
            for (int m = 0; m < 2; ++m)
                O[m][n] = __builtin_amdgcn_mfma_f32_16x16x32_bf16(pa[m], wb, O[m][n], 0, 0, 0);
        }
    }
#pragma unroll
    for (int m = 0; m < 2; ++m)
#pragma unroll
        for (int i = 0; i < 4; ++i) {
            float inv = 1.f / lsum[m][i];
            int gm = rbase + (m << 4) + (g << 2) + i;
#pragma unroll
            for (int n = 0; n < 4; ++n)
                o[(size_t)gm * DIMF + (h << 6) + (n << 4) + rA] =
                    __float2bfloat16(O[m][n][i] * inv);
        }
}

// ---------------- resconv (33-tap along seq): out = bf16(oin + conv)
__global__ __launch_bounds__(256) void resconv_tile_k(const __hip_bfloat16* __restrict__ qkvb16,
    const float* __restrict__ rw, const __hip_bfloat16* __restrict__ oin,
    __hip_bfloat16* __restrict__ oout)
{
    int cg = blockIdx.y;
    int t0 = blockIdx.x << 7;
    int tid = threadIdx.x;
    int lane = tid & 63, w = tid >> 6;
    __shared__ float vt[160][64];
    __shared__ float wr[33];
    if (tid < 33) wr[tid] = rw[cg * 33 + tid];
    for (int e = tid; e < 160 * 64; e += 256) {
        int tt = e >> 6, l = e & 63;
        int t = t0 - 16 + tt;
        vt[tt][l] = (t >= 0 && t < NP)
            ? __bfloat162float(qkvb16[(size_t)t * QKVW + 1024 + (cg << 6) + l]) : 0.f;
    }
    __syncthreads();
    for (int i = 0; i < 32; ++i) {
        int tl = (w << 5) + i;
        float acc = 0.f;
#pragma unroll
        for (int ky = 0; ky < 33; ++ky) acc += wr[ky] * vt[tl + ky][lane];
        size_t oi = (size_t)(t0 + tl) * DIMF + (cg << 6) + lane;
        oout[oi] = __float2bfloat16(__bfloat162float(oin[oi]) + acc);
    }
}

// ---------------- PPEG v3: 32 ch/block, float2/thread, conflict-free bf16 LDS
__global__ __launch_bounds__(256) void ppeg3_k(const float* __restrict__ x,
    const float* __restrict__ w7, const float* __restrict__ b7,
    const float* __restrict__ w5, const float* __restrict__ b5,
    const float* __restrict__ w3, const float* __restrict__ b3,
    float* __restrict__ outfeat)
{
    int cg = blockIdx.y;
    int ty0 = (blockIdx.x >> 4) << 3, tx0 = (blockIdx.x & 15) << 3;
    int tid = threadIdx.x;
    int cgi = tid & 15;
    int xo = (tid >> 4) & 7;
    int yb0 = (tid >> 7) << 2;
    int c = (cg << 5) + (cgi << 1);
    const float* feat = x + DIMF;
    __shared__ __align__(16) __hip_bfloat16 tile[196][32];
    __shared__ __align__(16) __hip_bfloat16 ws7[49][32];
    __shared__ __align__(16) __hip_bfloat16 ws5[25][32];
    __shared__ __align__(16) __hip_bfloat16 ws3[9][32];
    for (int e = tid; e < 49 * 32; e += 256) {
        int t = e >> 5, cl = e & 31;
        ws7[t][cl] = __float2bfloat16(w7[(size_t)((cg << 5) + cl) * 49 + t]);
    }
    for (int e = tid; e < 25 * 32; e += 256) {
        int t = e >> 5, cl = e & 31;
        ws5[t][cl] = __float2bfloat16(w5[(size_t)((cg << 5) + cl) * 25 + t]);
    }
    for (int e = tid; e < 9 * 32; e += 256) {
        int t = e >> 5, cl = e & 31;
        ws3[t][cl] = __float2bfloat16(w3[(size_t)((cg << 5) + cl) * 9 + t]);
    }
    for (int e = tid; e < 196 * 16; e += 256) {
        int sp = e >> 4, cp = (e & 15) << 1;
        int yy = ty0 - 3 + sp / 14, xc = tx0 - 3 + sp % 14;
        float2 v = make_float2(0.f, 0.f);
        if ((unsigned)yy < 128u && (unsigned)xc < 128u)
            v = *(const float2*)&feat[(size_t)(yy * 128 + xc) * DIMF + (cg << 5) + cp];
        *(unsigned*)&tile[sp][cp] = f2b16(v.x, v.y);
    }
    __syncthreads();
    float2 bs7 = *(const float2*)&b7[c], bs5 = *(const float2*)&b5[c], bs3 = *(const float2*)&b3[c];
    float bsx = bs7.x + bs5.x + bs3.x, bsy = bs7.y + bs5.y + bs3.y;
    float2 acc[4];
#pragma unroll
    for (int o = 0; o < 4; ++o) {
        float2 idv = *(const float2*)&feat[(size_t)((ty0 + yb0 + o) * 128 + tx0 + xo) * DIMF + c];
        acc[o].x = idv.x + bsx;
        acc[o].y = idv.y + bsy;
    }
    int c2 = cgi << 1;
#pragma unroll
    for (int kx = 0; kx < 7; ++kx) {
        float2 wc[7];
#pragma unroll
        for (int j = 0; j < 7; ++j) wc[j] = b2f(&ws7[j * 7 + kx][c2]);
#pragma unroll
        for (int r = 0; r < 10; ++r) {
            float2 v = b2f(&tile[(yb0 + r) * 14 + xo + kx][c2]);
#pragma unroll
            for (int o = 0; o < 4; ++o) {
                int ky = r - o;
                if (ky >= 0 && ky < 7) {
                    acc[o].x += wc[ky].x * v.x; acc[o].y += wc[ky].y * v.y;
                }
            }
        }
    }
#pragma unroll
    for (int kx = 0; kx < 5; ++kx) {
        float2 wc[5];
#pragma unroll
        for (int j = 0; j < 5; ++j) wc[j] = b2f(&ws5[j * 5 + kx][c2]);
#pragma unroll
        for (int r = 0; r < 8; ++r) {
            float2 v = b2f(&tile[(yb0 + 1 + r) * 14 + xo + 1 + kx][c2]);
#pragma unroll
            for (int o = 0; o < 4; ++o) {
                int ky = r - o;
                if (ky >= 0 && ky < 5) {
                    acc[o].x += wc[ky].x * v.x; acc[o].y += wc[ky].y * v.y;
                }
            }
        }
    }
#pragma unroll
    for (int kx = 0; kx < 3; ++kx) {
        float2 wc[3];
#pragma unroll
        for (int j = 0; j < 3; ++j) wc[j] = b2f(&ws3[j * 3 + kx][c2]);
#pragma unroll
        for (int r = 0; r < 6; ++r) {
            float2 v = b2f(&tile[(yb0 + 2 + r) * 14 + xo + 2 + kx][c2]);
#pragma unroll
            for (int o = 0; o < 4; ++o) {
                int ky = r - o;
                if (ky >= 0 && ky < 3) {
                    acc[o].x += wc[ky].x * v.x; acc[o].y += wc[ky].y * v.y;
                }
            }
        }
    }
#pragma unroll
    for (int o = 0; o < 4; ++o)
        *(float2*)&outfeat[(size_t)((ty0 + yb0 + o) * 128 + tx0 + xo) * DIMF + c] = acc[o];
}

// ---------------- final LN(row0) + 2-class head + softmax + argmax
__global__ __launch_bounds__(64) void head_k(const float* __restrict__ x,
    const float* __restrict__ g, const float* __restrict__ b,
    const float* __restrict__ w, const float* __restrict__ bias, float* __restrict__ out)
{
    int lane = threadIdx.x;
    float v[8], s = 0.f;
#pragma unroll
    for (int i = 0; i < 8; ++i) { v[i] = x[i * 64 + lane]; s += v[i]; }
#pragma unroll
    for (int off = 32; off; off >>= 1) s += __shfl_xor(s, off);
    float mu = s * (1.f / 512.f);
    float vs = 0.f;
#pragma unroll
    for (int i = 0; i < 8; ++i) { float d = v[i] - mu; vs += d * d; }
#pragma unroll
    for (int off = 32; off; off >>= 1) vs += __shfl_xor(vs, off);
    float rstd = rsqrtf(vs * (1.f / 512.f) + 1e-5f);
    float l0 = 0.f, l1 = 0.f;
#pragma unroll
    for (int i = 0; i < 8; ++i) {
        int d = i * 64 + lane;
        float hn = (v[i] - mu) * rstd * g[d] + b[d];
        l0 += hn * w[d * 2];
        l1 += hn * w[d * 2 + 1];
    }
#pragma unroll
    for (int off = 32; off; off >>= 1) { l0 += __shfl_xor(l0, off); l1 += __shfl_xor(l1, off); }
    if (lane == 0) {
        l0 += bias[0]; l1 += bias[1];
        float m = fmaxf(l0, l1);
        float e0 = __expf(l0 - m), e1 = __expf(l1 - m);
        float ss = e0 + e1;
        out[0] = l0; out[1] = l1;
        out[2] = e0 / ss; out[3] = e1 / ss;
        out[4] = (l1 > l0) ? 1.f : 0.f;
    }
}

extern "C" void kernel_launch(void* const* d_in, const int* in_sizes, int n_in,
                              void* d_out, int out_size, void* d_ws, size_t ws_size,
                              hipStream_t stream)
{
    (void)in_sizes; (void)n_in; (void)out_size; (void)ws_size;
    const float* data   = (const float*)d_in[0];
    const float* fc1_w  = (const float*)d_in[1];
    const float* fc1_b  = (const float*)d_in[2];
    const float* cls    = (const float*)d_in[3];
    const float* l1_ng  = (const float*)d_in[4];
    const float* l1_nb  = (const float*)d_in[5];
    const float* l1_qkv = (const float*)d_in[6];
    const float* l1_ow  = (const float*)d_in[7];
    const float* l1_ob  = (const float*)d_in[8];
    const float* l1_rw  = (const float*)d_in[9];
    const float* l2_ng  = (const float*)d_in[10];
    const float* l2_nb  = (const float*)d_in[11];
    const float* l2_qkv = (const float*)d_in[12];
    const float* l2_ow  = (const float*)d_in[13];
    const float* l2_ob  = (const float*)d_in[14];
    const float* l2_rw  = (const float*)d_in[15];
    const float* p_w7   = (const float*)d_in[16];
    const float* p_b7   = (const float*)d_in[17];
    const float* p_w5   = (const float*)d_in[18];
    const float* p_b5   = (const float*)d_in[19];
    const float* p_w3   = (const float*)d_in[20];
    const float* p_b3   = (const float*)d_in[21];
    const float* n_g    = (const float*)d_in[22];
    const float* n_b    = (const float*)d_in[23];
    const float* fc2_w  = (const float*)d_in[24];
    const float* fc2_b  = (const float*)d_in[25];

    char* base = (char*)d_ws;
    auto carve = [&](size_t bytes) { char* p = base; base += (bytes + 255) & ~(size_t)255; return p; };
    float* x               = (float*)carve((size_t)NT * DIMF * 4);
    float* x2              = (float*)carve((size_t)NT * DIMF * 4);
    __hip_bfloat16* xp16   = (__hip_bfloat16*)carve((size_t)NP * DIMF * 2);   // alias: obuf2
    __hip_bfloat16* qkvb16 = (__hip_bfloat16*)carve((size_t)NP * QKVW * 2);   // alias: data16
    __hip_bfloat16* vT16   = (__hip_bfloat16*)carve((size_t)NHEAD * DH * NP * 2);
    __hip_bfloat16* obuf16 = (__hip_bfloat16*)carve((size_t)NP * DIMF * 2);
    __hip_bfloat16* wT     = (__hip_bfloat16*)carve((size_t)QKVW * DIMF * 2);
    float* ql              = (float*)carve(131072 * 4);
    float* kl              = (float*)carve(131072 * 4);
    __hip_bfloat16* ql16   = (__hip_bfloat16*)carve(131072 * 2);
    __hip_bfloat16* kl16   = (__hip_bfloat16*)carve(131072 * 2);
    __hip_bfloat16* wmT16  = (__hip_bfloat16*)carve(131072 * 2);
    float* a2              = (float*)carve(524288 * 4);
    __hip_bfloat16* a2_16  = (__hip_bfloat16*)carve(524288 * 2);
    __hip_bfloat16* zrA    = (__hip_bfloat16*)carve(524288 * 2);
    __hip_bfloat16* zrB    = (__hip_bfloat16*)carve(524288 * 2);
    __hip_bfloat16* ztA    = (__hip_bfloat16*)carve(524288 * 2);
    __hip_bfloat16* ztB    = (__hip_bfloat16*)carve(524288 * 2);
    __hip_bfloat16* xz16   = (__hip_bfloat16*)carve(524288 * 2);
    __hip_bfloat16* t1T16  = (__hip_bfloat16*)carve(524288 * 2);
    __hip_bfloat16* a3vT16 = (__hip_bfloat16*)carve(131072 * 2);
    float* opart = (float*)carve((size_t)64 * A3V_TC * 2048 * 4);
    float* mpart = (float*)carve((size_t)64 * A3V_TC * 32 * 4);
    float* lpart = (float*)carve((size_t)64 * A3V_TC * 32 * 4);
    __hip_bfloat16* obuf2  = xp16;
    __hip_bfloat16* data16 = qkvb16;

    // ---- stem
    cvt_k<<<(16384 * 1024 / 4 + 255) / 256, 256, 0, stream>>>(
        (const float4*)data, (ushort4*)data16, 16384 * 1024 / 4);
    transcvt_k<<<(DIMF / 32) * (1024 / 32), 256, 0, stream>>>(fc1_w, wT, 1024, DIMF);
    gemm_bf16_k<<<dim3(DIMF / 128, 16384 / 128), 256, 0, stream>>>(
        data16, wT, fc1_b, nullptr, x + DIMF, nullptr, 16384, DIMF, 1024, 16384, 1);
    hipMemcpyAsync(x, cls, DIMF * sizeof(float), hipMemcpyDeviceToDevice, stream);

    auto layer = [&](float* xv, const float* ng, const float* nb, const float* qw,
                     const float* ow, const float* ob, const float* rw) {
        hipMemsetAsync(xp16, 0, (size_t)PADR * DIMF * 2, stream);
        ln_k<<<NT, 64, 0, stream>>>(xv, ng, nb, xp16 + (size_t)PADR * DIMF, NT);
        transcvt_k<<<(QKVW / 32) * (DIMF / 32), 256, 0, stream>>>(qw, wT, DIMF, QKVW);
        gemm_bf16_k<<<dim3(QKVW / 128, NP / 128), 256, 0, stream>>>(
            xp16, wT, nullptr, nullptr, nullptr, qkvb16, NP, QKVW, DIMF, NP, 0);
        vtrans_k<<<dim3(NP / 64, NHEAD), 256, 0, stream>>>(qkvb16, vT16);
        landmark_k<<<NHEAD * NLM, 256, 0, stream>>>(qkvb16, ql, kl, ql16, kl16);
        a2_k<<<NHEAD * NLM, 256, 0, stream>>>(ql, kl, a2, a2_16);
        zinit_k<<<NHEAD, 256, 0, stream>>>(a2, zrA, ztA);
        {
            const __hip_bfloat16* a2c = a2_16;
            __hip_bfloat16 *p0 = zrA, *p1 = zrB, *p2 = ztA, *p3 = ztB, *p4 = xz16, *p5 = t1T16;
            void* kargs[] = { (void*)&a2c, (void*)&p0, (void*)&p1, (void*)&p2,
                              (void*)&p3, (void*)&p4, (void*)&p5 };
            hipLaunchCooperativeKernel((const void*)pinv_coop_k, dim3(32), dim3(256),
                                       kargs, 0, stream);
        }
        a3v_flash_k<<<dim3(32, A3V_TC), 128, 0, stream>>>(ql16, qkvb16, vT16, opart, mpart, lpart);
        a3v_comb_k<<<64, 64, 0, stream>>>(opart, mpart, lpart, a3vT16);
        wm_k<<<NHEAD, 256, 0, stream>>>(zrA, a3vT16, wmT16);   // 6 iters -> final in zrA
        attnout_mfma_k<<<dim3(NP / 64, NHEAD), 128, 0, stream>>>(qkvb16, kl16, wmT16, obuf16);
        resconv_tile_k<<<dim3(NP / 128, NHEAD), 256, 0, stream>>>(qkvb16, rw, obuf16, obuf2);
        transcvt_k<<<(DIMF / 32) * (DIMF / 32), 256, 0, stream>>>(ow, wT, DIMF, DIMF);
        gemm_bf16_k<<<dim3(DIMF / 128, (NT + 127) / 128), 256, 0, stream>>>(
            obuf2 + (size_t)PADR * DIMF, wT, ob, xv, xv, nullptr, NT, DIMF, DIMF, NT, 0);
    };

    layer(x, l1_ng, l1_nb, l1_qkv, l1_ow, l1_ob, l1_rw);

    ppeg3_k<<<dim3(256, 16), 256, 0, stream>>>(x, p_w7, p_b7, p_w5, p_b5, p_w3, p_b3, x2 + DIMF);
    hipMemcpyAsync(x2, x, DIMF * sizeof(float), hipMemcpyDeviceToDevice, stream);

    layer(x2, l2_ng, l2_nb, l2_qkv, l2_ow, l2_ob, l2_rw);

    head_k<<<1, 64, 0, stream>>>(x2, n_g, n_b, fc2_w, fc2_b, (float*)d_out);
}

// Round 10
// 1411.773 us; speedup vs baseline: 1.1141x; 1.1141x over previous
//
#include <hip/hip_runtime.h>
#include <hip/hip_bf16.h>

// TransMIL forward. Round 10: consolidation — single-buffer MFMA GEMM with
// bijective XCD swizzle (r8-proven FETCH win), pgemm1/pgemm3 pinv pair (r7),
// bf16 attn-out path, conflict-free PPEG.

#define NT 16385
#define NP 16640
#define PADR 255
#define DIMF 512
#define QKVW 1536
#define NHEAD 8
#define DH 64
#define NLM 256
#define LSEG 65
#define A3V_TC 20

typedef short bf16x8 __attribute__((ext_vector_type(8)));
typedef short bf16x4 __attribute__((ext_vector_type(4)));
typedef float f32x4 __attribute__((ext_vector_type(4)));

__device__ __forceinline__ void gload_lds16(const void* g, void* l) {
    __builtin_amdgcn_global_load_lds(
        (const __attribute__((address_space(1))) void*)g,
        (__attribute__((address_space(3))) void*)l, 16, 0, 0);
}

__device__ __forceinline__ float2 b2f(const __hip_bfloat16* p) {
    ushort2 u = *(const ushort2*)p;
    float2 r;
    r.x = __uint_as_float((unsigned)u.x << 16);
    r.y = __uint_as_float((unsigned)u.y << 16);
    return r;
}

__device__ __forceinline__ unsigned f2b16(float a, float b) {
    union { unsigned u; __hip_bfloat16 h[2]; } c;
    c.h[0] = __float2bfloat16(a); c.h[1] = __float2bfloat16(b);
    return c.u;
}

__device__ __forceinline__ bf16x4 f4b(float a, float b, float c, float d) {
    union { bf16x4 v; __hip_bfloat16 h[4]; } u;
    u.h[0] = __float2bfloat16(a); u.h[1] = __float2bfloat16(b);
    u.h[2] = __float2bfloat16(c); u.h[3] = __float2bfloat16(d);
    return u.v;
}

// ---------------- bf16 MFMA GEMM (single-buffer 32KB LDS + bijective XCD swizzle)
__global__ __launch_bounds__(256) void gemm_bf16_k(
    const __hip_bfloat16* __restrict__ A, const __hip_bfloat16* __restrict__ BT,
    const float* __restrict__ bias, const float* __restrict__ Cacc,
    float* __restrict__ C, __hip_bfloat16* __restrict__ C16,
    int M, int N, int K, int MA, int relu)
{
    __shared__ __align__(16) __hip_bfloat16 Asl[128 * 64];
    __shared__ __align__(16) __hip_bfloat16 Bsl[128 * 64];
    int tid = threadIdx.x;
    int wid = tid >> 6, lane = tid & 63;
    int nwg = (int)(gridDim.x * gridDim.y);
    int orig = (int)(blockIdx.y * gridDim.x + blockIdx.x);
    int qq = nwg >> 3, rr = nwg & 7;
    int xcd = orig & 7, idx = orig >> 3;
    int wg = (xcd < rr ? xcd * (qq + 1) : rr * (qq + 1) + (xcd - rr) * qq) + idx;
    int m0 = (wg / (int)gridDim.x) << 7, n0 = (wg % (int)gridDim.x) << 7;
    int wr = (wid >> 1) << 6, wc = (wid & 1) << 6;
    f32x4 acc[4][4] = {};
    int lr = lane >> 3, lk = (lane & 7) << 3;
    for (int kt = 0; kt < K; kt += 64) {
#pragma unroll
        for (int i = 0; i < 4; ++i) {
            int ch = wid * 4 + i;
            int rowA = m0 + ch * 8 + lr;
            rowA = rowA < MA ? rowA : (MA - 1);
            gload_lds16(A + (size_t)rowA * K + kt + lk, &Asl[ch * 512]);
            int rowB = n0 + ch * 8 + lr;
            gload_lds16(BT + (size_t)rowB * K + kt + lk, &Bsl[ch * 512]);
        }
        __syncthreads();
#pragma unroll
        for (int ks = 0; ks < 2; ++ks) {
            int kb = ks * 32 + (lane >> 4) * 8;
            bf16x8 af[4], bfr[4];
#pragma unroll
            for (int m = 0; m < 4; ++m)
                af[m] = *(const bf16x8*)&Asl[(wr + m * 16 + (lane & 15)) * 64 + kb];
#pragma unroll
            for (int n = 0; n < 4; ++n)
                bfr[n] = *(const bf16x8*)&Bsl[(wc + n * 16 + (lane & 15)) * 64 + kb];
#pragma unroll
            for (int m = 0; m < 4; ++m)
#pragma unroll
                for (int n = 0; n < 4; ++n)
                    acc[m][n] = __builtin_amdgcn_mfma_f32_16x16x32_bf16(
                        af[m], bfr[n], acc[m][n], 0, 0, 0);
        }
        __syncthreads();
    }
    int cr = (lane >> 4) << 2, cc = lane & 15;
#pragma unroll
    for (int m = 0; m < 4; ++m) {
#pragma unroll
        for (int i = 0; i < 4; ++i) {
            int gm = m0 + wr + m * 16 + cr + i;
            if (gm >= M) continue;
#pragma unroll
            for (int n = 0; n < 4; ++n) {
                int gn = n0 + wc + n * 16 + cc;
                float v = acc[m][n][i];
                if (bias) v += bias[gn];
                if (Cacc) v += Cacc[(size_t)gm * N + gn];
                if (relu) v = fmaxf(v, 0.f);
                if (C16) C16[(size_t)gm * N + gn] = __float2bfloat16(v);
                else C[(size_t)gm * N + gn] = v;
            }
        }
    }
}

// ---------------- fp32 [KxN] -> bf16 [NxK] tiled transpose-convert
__global__ __launch_bounds__(256) void transcvt_k(const float* __restrict__ W,
    __hip_bfloat16* __restrict__ WT, int K, int N)
{
    __shared__ float t[32][33];
    int nt = N >> 5;
    int n0 = (blockIdx.x % nt) << 5, k0 = (blockIdx.x / nt) << 5;
    int tx = threadIdx.x & 31, ty = threadIdx.x >> 5;
    for (int r = ty; r < 32; r += 8) t[r][tx] = W[(size_t)(k0 + r) * N + n0 + tx];
    __syncthreads();
    for (int r = ty; r < 32; r += 8)
        WT[(size_t)(n0 + r) * K + k0 + tx] = __float2bfloat16(t[tx][r]);
}

// ---------------- fp32 -> bf16 convert (vectorized)
__global__ __launch_bounds__(256) void cvt_k(const float4* __restrict__ in,
    ushort4* __restrict__ out, int n4)
{
    int i = blockIdx.x * 256 + threadIdx.x;
    if (i >= n4) return;
    float4 v = in[i];
    union { __hip_bfloat16 h[4]; ushort4 u; } cv;
    cv.h[0] = __float2bfloat16(v.x); cv.h[1] = __float2bfloat16(v.y);
    cv.h[2] = __float2bfloat16(v.z); cv.h[3] = __float2bfloat16(v.w);
    out[i] = cv.u;
}

// ---------------- v transpose: vT16[h][d][t]
__global__ __launch_bounds__(256) void vtrans_k(const __hip_bfloat16* __restrict__ qkvb16,
    __hip_bfloat16* __restrict__ vT16)
{
    int h = blockIdx.y;
    int t0 = blockIdx.x << 6;
    __shared__ float tile[64][65];
    int tid = threadIdx.x;
    for (int e = tid; e < 512; e += 256) {
        int r = e >> 3, c8 = (e & 7) << 3;
        union { bf16x8 v; __hip_bfloat16 hh[8]; } u;
        u.v = *(const bf16x8*)(qkvb16 + (size_t)(t0 + r) * QKVW + 1024 + (h << 6) + c8);
#pragma unroll
        for (int j = 0; j < 8; ++j) tile[r][c8 + j] = __bfloat162float(u.hh[j]);
    }
    __syncthreads();
    for (int e = tid; e < 512; e += 256) {
        int d = e >> 3, t8 = (e & 7) << 3;
        union { bf16x8 v; __hip_bfloat16 hh[8]; } u;
#pragma unroll
        for (int j = 0; j < 8; ++j) u.hh[j] = __float2bfloat16(tile[t8 + j][d]);
        *(bf16x8*)(vT16 + ((size_t)(h << 6) + d) * NP + t0 + t8) = u.v;
    }
}

// ---------------- LayerNorm per row (512) -> bf16 out
__global__ __launch_bounds__(64) void ln_k(const float* __restrict__ in,
    const float* __restrict__ g, const float* __restrict__ b,
    __hip_bfloat16* __restrict__ out, int rows)
{
    int r = blockIdx.x;
    if (r >= rows) return;
    int lane = threadIdx.x;
    const float* xr = in + (size_t)r * DIMF;
    float v[8], s = 0.f;
#pragma unroll
    for (int i = 0; i < 8; ++i) { v[i] = xr[i * 64 + lane]; s += v[i]; }
#pragma unroll
    for (int off = 32; off; off >>= 1) s += __shfl_xor(s, off);
    float mu = s * (1.f / 512.f);
    float vs = 0.f;
#pragma unroll
    for (int i = 0; i < 8; ++i) { float d = v[i] - mu; vs += d * d; }
#pragma unroll
    for (int off = 32; off; off >>= 1) vs += __shfl_xor(vs, off);
    float rstd = rsqrtf(vs * (1.f / 512.f) + 1e-5f);
    __hip_bfloat16* orow = out + (size_t)r * DIMF;
#pragma unroll
    for (int i = 0; i < 8; ++i) {
        int d = i * 64 + lane;
        orow[d] = __float2bfloat16((v[i] - mu) * rstd * g[d] + b[d]);
    }
}

// ---------------- landmark means, 4 waves split the 65-row sum
__global__ __launch_bounds__(256) void landmark_k(const __hip_bfloat16* __restrict__ qkvb16,
    float* __restrict__ ql, float* __restrict__ kl,
    __hip_bfloat16* __restrict__ ql16, __hip_bfloat16* __restrict__ kl16)
{
    int bx = blockIdx.x;
    int h = bx >> 8, j = bx & 255;
    int w = threadIdx.x >> 6, d = threadIdx.x & 63;
    __shared__ float pq[4][64], pk[4][64];
    float qs = 0.f, ks = 0.f;
    for (int u = w; u < LSEG; u += 4) {
        size_t addr = (size_t)(j * LSEG + u) * QKVW + (h << 6) + d;
        qs += __bfloat162float(qkvb16[addr]);
        ks += __bfloat162float(qkvb16[addr + 512]);
    }
    pq[w][d] = qs; pk[w][d] = ks;
    __syncthreads();
    if (threadIdx.x < 64) {
        float q = pq[0][d] + pq[1][d] + pq[2][d] + pq[3][d];
        float k = pk[0][d] + pk[1][d] + pk[2][d] + pk[3][d];
        float qm = q * (1.f / 65.f) * 0.125f;
        float km = k * (1.f / 65.f);
        ql[(size_t)bx * 64 + d] = qm;
        kl[(size_t)bx * 64 + d] = km;
        ql16[(size_t)bx * 64 + d] = __float2bfloat16(qm);
        kl16[(size_t)bx * 64 + d] = __float2bfloat16(km);
    }
}

// ---------------- a2 = softmax(q_l @ k_l^T); writes fp32 + bf16 row-major
__global__ __launch_bounds__(256) void a2_k(const float* __restrict__ ql,
    const float* __restrict__ kl, float* __restrict__ a2, __hip_bfloat16* __restrict__ a2_16)
{
    int h = blockIdx.x >> 8, i = blockIdx.x & 255;
    int j = threadIdx.x;
    __shared__ float qs[64];
    __shared__ float red[256];
    if (j < 64) qs[j] = ql[((size_t)(h << 8) + i) * 64 + j];
    __syncthreads();
    const float* kr = kl + ((size_t)(h << 8) + j) * 64;
    float s = 0.f;
#pragma unroll 8
    for (int d = 0; d < 64; ++d) s += qs[d] * kr[d];
    red[j] = s; __syncthreads();
    for (int st = 128; st; st >>= 1) { if (j < st) red[j] = fmaxf(red[j], red[j + st]); __syncthreads(); }
    float mx = red[0]; __syncthreads();
    float p = __expf(s - mx);
    red[j] = p; __syncthreads();
    for (int st = 128; st; st >>= 1) { if (j < st) red[j] += red[j + st]; __syncthreads(); }
    float v = p / red[0];
    a2[((size_t)h << 16) + i * 256 + j] = v;
    a2_16[((size_t)h << 16) + i * 256 + j] = __float2bfloat16(v);
}

// ---------------- pinv init: z = a2^T/(maxrow*maxcol); LDS-tiled transpose
__global__ __launch_bounds__(256) void zinit_k(const float* __restrict__ a2,
    __hip_bfloat16* __restrict__ zr16, __hip_bfloat16* __restrict__ zT16)
{
    int h = blockIdx.x, t = threadIdx.x;
    const float* X = a2 + ((size_t)h << 16);
    __shared__ float red[256];
    __shared__ float tl[64][65];
    float rs = 0.f;
    const float4* Xr = (const float4*)(X + (size_t)t * 256);
    for (int j = 0; j < 64; ++j) {
        float4 v = Xr[j];
        rs += fabsf(v.x) + fabsf(v.y) + fabsf(v.z) + fabsf(v.w);
    }
    red[t] = rs; __syncthreads();
    for (int st = 128; st; st >>= 1) { if (t < st) red[t] = fmaxf(red[t], red[t + st]); __syncthreads(); }
    float colv = red[0]; __syncthreads();
    float cs = 0.f;
    for (int i = 0; i < 256; ++i) cs += fabsf(X[i * 256 + t]);
    red[t] = cs; __syncthreads();
    for (int st = 128; st; st >>= 1) { if (t < st) red[t] = fmaxf(red[t], red[t + st]); __syncthreads(); }
    float rowv = red[0];
    float inv = 1.f / (colv * rowv);
    int cl = t & 63, rg = t >> 6;
    for (int tr = 0; tr < 4; ++tr)
        for (int tc = 0; tc < 4; ++tc) {
            __syncthreads();
#pragma unroll
            for (int k = 0; k < 16; ++k) {
                int rl = (k << 2) + rg;
                tl[rl][cl] = X[(size_t)(tr * 64 + rl) * 256 + tc * 64 + cl];
            }
            __syncthreads();
#pragma unroll
            for (int k = 0; k < 16; ++k) {
                int rl = (k << 2) + rg;
                zT16[((size_t)h << 16) + (size_t)(tr * 64 + rl) * 256 + tc * 64 + cl] =
                    __float2bfloat16(tl[rl][cl] * inv);
                zr16[((size_t)h << 16) + (size_t)(tc * 64 + rl) * 256 + tr * 64 + cl] =
                    __float2bfloat16(tl[cl][rl] * inv);
            }
        }
}

// ---------------- pinv G1: xz = a2 @ Z. Writes xz16 + t1T16=7I-xz^T.
__global__ __launch_bounds__(256) void pgemm1_k(
    const __hip_bfloat16* __restrict__ a2_16, const __hip_bfloat16* __restrict__ zT16,
    __hip_bfloat16* __restrict__ xz16, __hip_bfloat16* __restrict__ t1T16)
{
    int h = blockIdx.y, n0 = blockIdx.x << 6;
    int lane = threadIdx.x & 63;
    int r0 = (threadIdx.x >> 6) << 6;
    int rA = lane & 15, g = lane >> 4, kp = g << 3;
    const __hip_bfloat16* Ah = a2_16 + ((size_t)h << 16);
    const __hip_bfloat16* Bh = zT16 + ((size_t)h << 16);
    f32x4 acc[4][4] = {};
    for (int ks = 0; ks < 8; ++ks) {
        bf16x8 af[4], bfr[4];
#pragma unroll
        for (int m = 0; m < 4; ++m)
            af[m] = *(const bf16x8*)&Ah[(size_t)(r0 + m * 16 + rA) * 256 + ks * 32 + kp];
#pragma unroll
        for (int n = 0; n < 4; ++n)
            bfr[n] = *(const bf16x8*)&Bh[(size_t)(n0 + n * 16 + rA) * 256 + ks * 32 + kp];
#pragma unroll
        for (int m = 0; m < 4; ++m)
#pragma unroll
            for (int n = 0; n < 4; ++n)
                acc[m][n] = __builtin_amdgcn_mfma_f32_16x16x32_bf16(af[m], bfr[n], acc[m][n], 0, 0, 0);
    }
    __hip_bfloat16* xzh = xz16 + ((size_t)h << 16);
    __hip_bfloat16* t1h = t1T16 + ((size_t)h << 16);
#pragma unroll
    for (int m = 0; m < 4; ++m)
#pragma unroll
        for (int i = 0; i < 4; ++i) {
            int gr = r0 + m * 16 + (g << 2) + i;
#pragma unroll
            for (int n = 0; n < 4; ++n) {
                int gc = n0 + n * 16 + rA;
                float v = acc[m][n][i];
                xzh[(size_t)gr * 256 + gc] = __float2bfloat16(v);
                t1h[(size_t)gc * 256 + gr] = __float2bfloat16((gr == gc ? 7.f : 0.f) - v);
            }
        }
}

// ---------------- pinv G2+G3+G4 fused per column-stripe
__global__ __launch_bounds__(256) void pgemm3_k(
    const __hip_bfloat16* __restrict__ xz16, const __hip_bfloat16* __restrict__ t1T16,
    const __hip_bfloat16* __restrict__ zr16,
    __hip_bfloat16* __restrict__ znr16, __hip_bfloat16* __restrict__ znT16)
{
    __shared__ __align__(16) __hip_bfloat16 tA[64][264];
    __shared__ __align__(16) __hip_bfloat16 tB[64][264];
    int h = blockIdx.y, n0 = blockIdx.x << 6;
    int lane = threadIdx.x & 63;
    int r0 = (threadIdx.x >> 6) << 6;
    int rA = lane & 15, g = lane >> 4, kp = g << 3;
    const __hip_bfloat16* Xh = xz16 + ((size_t)h << 16);
    const __hip_bfloat16* T1h = t1T16 + ((size_t)h << 16);
    {
        f32x4 acc[4][4] = {};
        for (int ks = 0; ks < 8; ++ks) {
            bf16x8 af[4], bfr[4];
#pragma unroll
            for (int m = 0; m < 4; ++m)
                af[m] = *(const bf16x8*)&Xh[(size_t)(r0 + m * 16 + rA) * 256 + ks * 32 + kp];
#pragma unroll
            for (int n = 0; n < 4; ++n)
                bfr[n] = *(const bf16x8*)&T1h[(size_t)(n0 + n * 16 + rA) * 256 + ks * 32 + kp];
#pragma unroll
            for (int m = 0; m < 4; ++m)
#pragma unroll
                for (int n = 0; n < 4; ++n)
                    acc[m][n] = __builtin_amdgcn_mfma_f32_16x16x32_bf16(af[m], bfr[n], acc[m][n], 0, 0, 0);
        }
#pragma unroll
        for (int m = 0; m < 4; ++m)
#pragma unroll
            for (int n = 0; n < 4; ++n) {
                int gr0 = r0 + m * 16 + (g << 2);
                int cl = n * 16 + rA;
                *(bf16x4*)&tA[cl][gr0] = f4b(
                    ((gr0 + 0 == n0 + cl) ? 15.f : 0.f) - acc[m][n][0],
                    ((gr0 + 1 == n0 + cl) ? 15.f : 0.f) - acc[m][n][1],
                    ((gr0 + 2 == n0 + cl) ? 15.f : 0.f) - acc[m][n][2],
                    ((gr0 + 3 == n0 + cl) ? 15.f : 0.f) - acc[m][n][3]);
            }
    }
    __syncthreads();
    {
        f32x4 acc[4][4] = {};
        for (int ks = 0; ks < 8; ++ks) {
            bf16x8 af[4], bfr[4];
#pragma unroll
            for (int m = 0; m < 4; ++m)
                af[m] = *(const bf16x8*)&Xh[(size_t)(r0 + m * 16 + rA) * 256 + ks * 32 + kp];
#pragma unroll
            for (int n = 0; n < 4; ++n)
                bfr[n] = *(const bf16x8*)&tA[n * 16 + rA][ks * 32 + kp];
#pragma unroll
            for (int m = 0; m < 4; ++m)
#pragma unroll
                for (int n = 0; n < 4; ++n)
                    acc[m][n] = __builtin_amdgcn_mfma_f32_16x16x32_bf16(af[m], bfr[n], acc[m][n], 0, 0, 0);
        }
#pragma unroll
        for (int m = 0; m < 4; ++m)
#pragma unroll
            for (int n = 0; n < 4; ++n) {
                int gr0 = r0 + m * 16 + (g << 2);
                int cl = n * 16 + rA;
                *(bf16x4*)&tB[cl][gr0] = f4b(
                    ((gr0 + 0 == n0 + cl) ? 13.f : 0.f) - acc[m][n][0],
                    ((gr0 + 1 == n0 + cl) ? 13.f : 0.f) - acc[m][n][1],
                    ((gr0 + 2 == n0 + cl) ? 13.f : 0.f) - acc[m][n][2],
                    ((gr0 + 3 == n0 + cl) ? 13.f : 0.f) - acc[m][n][3]);
            }
    }
    __syncthreads();
    {
        const __hip_bfloat16* Zh = zr16 + ((size_t)h << 16);
        f32x4 acc[4][4] = {};
        for (int ks = 0; ks < 8; ++ks) {
            bf16x8 af[4], bfr[4];
#pragma unroll
            for (int m = 0; m < 4; ++m)
                af[m] = *(const bf16x8*)&Zh[(size_t)(r0 + m * 16 + rA) * 256 + ks * 32 + kp];
#pragma unroll
            for (int n = 0; n < 4; ++n)
                bfr[n] = *(const bf16x8*)&tB[n * 16 + rA][ks * 32 + kp];
#pragma unroll
            for (int m = 0; m < 4; ++m)
#pragma unroll
                for (int n = 0; n < 4; ++n)
                    acc[m][n] = __builtin_amdgcn_mfma_f32_16x16x32_bf16(af[m], bfr[n], acc[m][n], 0, 0, 0);
        }
        __hip_bfloat16* zrh = znr16 + ((size_t)h << 16);
        __hip_bfloat16* zth = znT16 + ((size_t)h << 16);
#pragma unroll
        for (int m = 0; m < 4; ++m)
#pragma unroll
            for (int i = 0; i < 4; ++i) {
                int gr = r0 + m * 16 + (g << 2) + i;
#pragma unroll
                for (int n = 0; n < 4; ++n) {
                    int gc = n0 + n * 16 + rA;
                    float v = 0.25f * acc[m][n][i];
                    zrh[(size_t)gr * 256 + gc] = __float2bfloat16(v);
                    zth[(size_t)gc * 256 + gr] = __float2bfloat16(v);
                }
            }
    }
}

// ---------------- wm = Zfinal @ a3v -> wmT16
__global__ __launch_bounds__(256) void wm_k(
    const __hip_bfloat16* __restrict__ zr16, const __hip_bfloat16* __restrict__ a3vT16,
    __hip_bfloat16* __restrict__ wmT16)
{
    int h = blockIdx.x;
    int lane = threadIdx.x & 63;
    int r0 = (threadIdx.x >> 6) << 6;
    int rA = lane & 15, g = lane >> 4, kp = g << 3;
    const __hip_bfloat16* Zh = zr16 + ((size_t)h << 16);
    const __hip_bfloat16* Bh = a3vT16 + ((size_t)h << 14);
    f32x4 acc[4][4] = {};
    for (int ks = 0; ks < 8; ++ks) {
        bf16x8 af[4], bfr[4];
#pragma unroll
        for (int m = 0; m < 4; ++m)
            af[m] = *(const bf16x8*)&Zh[(size_t)(r0 + m * 16 + rA) * 256 + ks * 32 + kp];
#pragma unroll
        for (int n = 0; n < 4; ++n)
            bfr[n] = *(const bf16x8*)&Bh[(size_t)(n * 16 + rA) * 256 + ks * 32 + kp];
#pragma unroll
        for (int m = 0; m < 4; ++m)
#pragma unroll
            for (int n = 0; n < 4; ++n)
                acc[m][n] = __builtin_amdgcn_mfma_f32_16x16x32_bf16(af[m], bfr[n], acc[m][n], 0, 0, 0);
    }
    __hip_bfloat16* Wh = wmT16 + ((size_t)h << 14);
#pragma unroll
    for (int m = 0; m < 4; ++m)
#pragma unroll
        for (int i = 0; i < 4; ++i) {
            int gr = r0 + m * 16 + (g << 2) + i;
#pragma unroll
            for (int n = 0; n < 4; ++n)
                Wh[(size_t)(n * 16 + rA) * 256 + gr] = __float2bfloat16(acc[m][n][i]);
        }
}

// ---------------- MFMA flash a3v partials
__global__ __launch_bounds__(128) void a3v_flash_k(
    const __hip_bfloat16* __restrict__ ql16, const __hip_bfloat16* __restrict__ qkvb16,
    const __hip_bfloat16* __restrict__ vT16,
    float* __restrict__ opart, float* __restrict__ mpart, float* __restrict__ lpart)
{
    int bx = blockIdx.x;
    int h = bx >> 2, qb = bx & 3;
    int tc = blockIdx.y;
    int wv = threadIdx.x >> 6;
    int lane = threadIdx.x & 63;
    int rA = lane & 15, g = lane >> 4, kp = g << 3;
    __shared__ __align__(16) __hip_bfloat16 Plds[2][32 * 64];
    char* P = (char*)&Plds[wv][0];

    bf16x8 qa[2][2];
    const __hip_bfloat16* qlh = ql16 + ((size_t)h << 14);
#pragma unroll
    for (int m = 0; m < 2; ++m)
#pragma unroll
        for (int ks = 0; ks < 2; ++ks)
            qa[m][ks] = *(const bf16x8*)(qlh +
                (size_t)((qb << 6) + (wv << 5) + (m << 4) + rA) * 64 + ks * 32 + kp);

    const __hip_bfloat16* kg = qkvb16 + 512 + (h << 6);
    const __hip_bfloat16* vg = vT16 + ((size_t)(h << 6)) * NP;

    f32x4 O[2][4] = {};
    float m_[2][4], l_[2][4];
#pragma unroll
    for (int m = 0; m < 2; ++m)
#pragma unroll
        for (int i = 0; i < 4; ++i) { m_[m][i] = -3e38f; l_[m][i] = 0.f; }

    for (int tile = tc * 13; tile < tc * 13 + 13; ++tile) {
        int t0 = tile << 6;
        f32x4 S[2][4] = {};
#pragma unroll
        for (int n = 0; n < 4; ++n)
#pragma unroll
            for (int ks = 0; ks < 2; ++ks) {
                bf16x8 kb = *(const bf16x8*)(kg + (size_t)(t0 + (n << 4) + rA) * QKVW + ks * 32 + kp);
                S[0][n] = __builtin_amdgcn_mfma_f32_16x16x32_bf16(qa[0][ks], kb, S[0][n], 0, 0, 0);
                S[1][n] = __builtin_amdgcn_mfma_f32_16x16x32_bf16(qa[1][ks], kb, S[1][n], 0, 0, 0);
            }
        float f_[2][4];
#pragma unroll
        for (int m = 0; m < 2; ++m)
#pragma unroll
            for (int i = 0; i < 4; ++i) {
                float mx = fmaxf(fmaxf(S[m][0][i], S[m][1][i]), fmaxf(S[m][2][i], S[m][3][i]));
#pragma unroll
                for (int msk = 8; msk; msk >>= 1) mx = fmaxf(mx, __shfl_xor(mx, msk));
                float mn = fmaxf(m_[m][i], mx);
                float f = __expf(m_[m][i] - mn);
                int r = (m << 4) + (g << 2) + i;
                int swz = (r & 7) << 4;
                float sum = 0.f;
#pragma unroll
                for (int n = 0; n < 4; ++n) {
                    float p = __expf(S[m][n][i] - mn);
                    sum += p;
                    int byte = (r << 7) + (((n << 4) + rA) << 1);
                    *(__hip_bfloat16*)(P + (byte ^ swz)) = __float2bfloat16(p);
                }
#pragma unroll
                for (int msk = 8; msk; msk >>= 1) sum += __shfl_xor(sum, msk);
                l_[m][i] = l_[m][i] * f + sum;
                m_[m][i] = mn;
                f_[m][i] = f;
            }
#pragma unroll
        for (int m = 0; m < 2; ++m)
#pragma unroll
            for (int i = 0; i < 4; ++i) {
                float f = f_[m][i];
#pragma unroll
                for (int n = 0; n < 4; ++n) O[m][n][i] *= f;
            }
#pragma unroll
        for (int ks2 = 0; ks2 < 2; ++ks2) {
            bf16x8 pa[2];
#pragma unroll
            for (int m = 0; m < 2; ++m) {
                int rr = (m << 4) + rA;
                int byte = (rr << 7) + ((ks2 * 32 + kp) << 1);
                pa[m] = *(const bf16x8*)(P + (byte ^ ((rr & 7) << 4)));
            }
#pragma unroll
            for (int n = 0; n < 4; ++n) {
                bf16x8 vb = *(const bf16x8*)(vg + (size_t)((n << 4) + rA) * NP + t0 + ks2 * 32 + kp);
                O[0][n] = __builtin_amdgcn_mfma_f32_16x16x32_bf16(pa[0], vb, O[0][n], 0, 0, 0);
                O[1][n] = __builtin_amdgcn_mfma_f32_16x16x32_bf16(pa[1], vb, O[1][n], 0, 0, 0);
            }
        }
    }
    int pb2 = (bx << 1) | wv;
    size_t obase = ((size_t)pb2 * A3V_TC + tc) * 2048;
#pragma unroll
    for (int m = 0; m < 2; ++m)
#pragma unroll
        for (int i = 0; i < 4; ++i) {
            int r = (m << 4) + (g << 2) + i;
#pragma unroll
            for (int n = 0; n < 4; ++n)
                opart[obase + (size_t)r * 64 + (n << 4) + rA] = O[m][n][i];
            if (rA == 0) {
                mpart[((size_t)pb2 * A3V_TC + tc) * 32 + r] = m_[m][i];
                lpart[((size_t)pb2 * A3V_TC + tc) * 32 + r] = l_[m][i];
            }
        }
}

// ---------------- a3v combine -> a3vT16[h][d][j] bf16
__global__ __launch_bounds__(64) void a3v_comb_k(const float* __restrict__ opart,
    const float* __restrict__ mpart, const float* __restrict__ lpart,
    __hip_bfloat16* __restrict__ a3vT16)
{
    int pb = blockIdx.x, d = threadIdx.x;
    int h = pb >> 3;
    for (int r = 0; r < 32; ++r) {
        float M = -3e38f;
        for (int tc = 0; tc < A3V_TC; ++tc)
            M = fmaxf(M, mpart[((size_t)pb * A3V_TC + tc) * 32 + r]);
        float L = 0.f, od = 0.f;
        for (int tc = 0; tc < A3V_TC; ++tc) {
            float w = __expf(mpart[((size_t)pb * A3V_TC + tc) * 32 + r] - M);
            L += lpart[((size_t)pb * A3V_TC + tc) * 32 + r] * w;
            od += w * opart[((size_t)pb * A3V_TC + tc) * 2048 + (size_t)r * 64 + d];
        }
        int j = ((pb & 7) << 5) + r;
        a3vT16[((size_t)((h << 6) + d) << 8) + j] = __float2bfloat16(od / L);
    }
}

// ---------------- MFMA fused sim1-softmax @ Wm -> bf16 out
__global__ __launch_bounds__(128) void attnout_mfma_k(
    const __hip_bfloat16* __restrict__ qkvb16, const __hip_bfloat16* __restrict__ kl16,
    const __hip_bfloat16* __restrict__ wmT16, __hip_bfloat16* __restrict__ o)
{
    int h = blockIdx.y;
    int rbase = (blockIdx.x << 6) + ((threadIdx.x >> 6) << 5);
    int lane = threadIdx.x & 63;
    int rA = lane & 15;
    int g = lane >> 4;
    int kp = g << 3;
    __shared__ __align__(16) __hip_bfloat16 Plds[2][32 * 256];
    char* P = (char*)&Plds[threadIdx.x >> 6][0];

    bf16x8 qa[2][2];
#pragma unroll
    for (int m = 0; m < 2; ++m)
#pragma unroll
        for (int ks = 0; ks < 2; ++ks)
            qa[m][ks] = *(const bf16x8*)(qkvb16 +
                (size_t)(rbase + m * 16 + rA) * QKVW + (h << 6) + ks * 32 + kp);

    const __hip_bfloat16* klh = kl16 + ((size_t)h << 14);
    f32x4 S[2][16] = {};
#pragma unroll
    for (int n = 0; n < 16; ++n) {
#pragma unroll
        for (int ks = 0; ks < 2; ++ks) {
            bf16x8 kb = *(const bf16x8*)(klh + (size_t)((n << 4) + rA) * 64 + ks * 32 + kp);
            S[0][n] = __builtin_amdgcn_mfma_f32_16x16x32_bf16(qa[0][ks], kb, S[0][n], 0, 0, 0);
            S[1][n] = __builtin_amdgcn_mfma_f32_16x16x32_bf16(qa[1][ks], kb, S[1][n], 0, 0, 0);
        }
    }
#pragma unroll
    for (int m = 0; m < 2; ++m)
#pragma unroll
        for (int n = 0; n < 16; ++n) S[m][n] *= 0.125f;

    float lsum[2][4];
#pragma unroll
    for (int m = 0; m < 2; ++m)
#pragma unroll
        for (int i = 0; i < 4; ++i) {
            float mx = -3e38f;
#pragma unroll
            for (int n = 0; n < 16; ++n) mx = fmaxf(mx, S[m][n][i]);
#pragma unroll
            for (int msk = 8; msk; msk >>= 1) mx = fmaxf(mx, __shfl_xor(mx, msk));
            float sum = 0.f;
            int r = (m << 4) + (g << 2) + i;
            int swz = (r & 7) << 4;
#pragma unroll
            for (int n = 0; n < 16; ++n) {
                float p = __expf(S[m][n][i] - mx);
                sum += p;
                int byte = (r << 9) + (((n << 4) + rA) << 1);
                *(__hip_bfloat16*)(P + (byte ^ swz)) = __float2bfloat16(p);
            }
#pragma unroll
            for (int msk = 8; msk; msk >>= 1) sum += __shfl_xor(sum, msk);
            lsum[m][i] = sum;
        }

    const __hip_bfloat16* wmh = wmT16 + ((size_t)h << 14);
    f32x4 O[2][4] = {};
#pragma unroll
    for (int kc = 0; kc < 8; ++kc) {
        bf16x8 pa[2];
#pragma unroll
        for (int m = 0; m < 2; ++m) {
            int rr = (m << 4) + rA;
            int byte = (rr << 9) + (((kc << 5) + kp) << 1);
            pa[m] = *(const bf16x8*)(P + (byte ^ ((rr & 7) << 4)));
        }
#pragma unroll
        for (int n = 0; n < 4; ++n) {
            bf16x8 wb = *(const bf16x8*)(wmh + (size_t)((n << 4) + rA) * 256 + (kc << 5) + kp);
#pragma unroll
            for (int m = 0; m < 2; ++m)
                O[m][n] = __builtin_amdgcn_mfma_f32_16x16x32_bf16(pa[m], wb, O[m][n], 0, 0, 0);
        }
    }
#pragma unroll
    for (int m = 0; m < 2; ++m)
#pragma unroll
        for (int i = 0; i < 4; ++i) {
            float inv = 1.f / lsum[m][i];
            int gm = rbase + (m << 4) + (g << 2) + i;
#pragma unroll
            for (int n = 0; n < 4; ++n)
                o[(size_t)gm * DIMF + (h << 6) + (n << 4) + rA] =
                    __float2bfloat16(O[m][n][i] * inv);
        }
}

// ---------------- resconv (33-tap along seq): out = bf16(oin + conv)
__global__ __launch_bounds__(256) void resconv_tile_k(const __hip_bfloat16* __restrict__ qkvb16,
    const float* __restrict__ rw, const __hip_bfloat16* __restrict__ oin,
    __hip_bfloat16* __restrict__ oout)
{
    int cg = blockIdx.y;
    int t0 = blockIdx.x << 7;
    int tid = threadIdx.x;
    int lane = tid & 63, w = tid >> 6;
    __shared__ float vt[160][64];
    __shared__ float wr[33];
    if (tid < 33) wr[tid] = rw[cg * 33 + tid];
    for (int e = tid; e < 160 * 64; e += 256) {
        int tt = e >> 6, l = e & 63;
        int t = t0 - 16 + tt;
        vt[tt][l] = (t >= 0 && t < NP)
            ? __bfloat162float(qkvb16[(size_t)t * QKVW + 1024 + (cg << 6) + l]) : 0.f;
    }
    __syncthreads();
    for (int i = 0; i < 32; ++i) {
        int tl = (w << 5) + i;
        float acc = 0.f;
#pragma unroll
        for (int ky = 0; ky < 33; ++ky) acc += wr[ky] * vt[tl + ky][lane];
        size_t oi = (size_t)(t0 + tl) * DIMF + (cg << 6) + lane;
        oout[oi] = __float2bfloat16(__bfloat162float(oin[oi]) + acc);
    }
}

// ---------------- PPEG v3: 32 ch/block, float2/thread, conflict-free bf16 LDS
__global__ __launch_bounds__(256) void ppeg3_k(const float* __restrict__ x,
    const float* __restrict__ w7, const float* __restrict__ b7,
    const float* __restrict__ w5, const float* __restrict__ b5,
    const float* __restrict__ w3, const float* __restrict__ b3,
    float* __restrict__ outfeat)
{
    int cg = blockIdx.y;
    int ty0 = (blockIdx.x >> 4) << 3, tx0 = (blockIdx.x & 15) << 3;
    int tid = threadIdx.x;
    int cgi = tid & 15;
    int xo = (tid >> 4) & 7;
    int yb0 = (tid >> 7) << 2;
    int c = (cg << 5) + (cgi << 1);
    const float* feat = x + DIMF;
    __shared__ __align__(16) __hip_bfloat16 tile[196][32];
    __shared__ __align__(16) __hip_bfloat16 ws7[49][32];
    __shared__ __align__(16) __hip_bfloat16 ws5[25][32];
    __shared__ __align__(16) __hip_bfloat16 ws3[9][32];
    for (int e = tid; e < 49 * 32; e += 256) {
        int t = e >> 5, cl = e & 31;
        ws7[t][cl] = __float2bfloat16(w7[(size_t)((cg << 5) + cl) * 49 + t]);
    }
    for (int e = tid; e < 25 * 32; e += 256) {
        int t = e >> 5, cl = e & 31;
        ws5[t][cl] = __float2bfloat16(w5[(size_t)((cg << 5) + cl) * 25 + t]);
    }
    for (int e = tid; e < 9 * 32; e += 256) {
        int t = e >> 5, cl = e & 31;
        ws3[t][cl] = __float2bfloat16(w3[(size_t)((cg << 5) + cl) * 9 + t]);
    }
    for (int e = tid; e < 196 * 16; e += 256) {
        int sp = e >> 4, cp = (e & 15) << 1;
        int yy = ty0 - 3 + sp / 14, xc = tx0 - 3 + sp % 14;
        float2 v = make_float2(0.f, 0.f);
        if ((unsigned)yy < 128u && (unsigned)xc < 128u)
            v = *(const float2*)&feat[(size_t)(yy * 128 + xc) * DIMF + (cg << 5) + cp];
        *(unsigned*)&tile[sp][cp] = f2b16(v.x, v.y);
    }
    __syncthreads();
    float2 bs7 = *(const float2*)&b7[c], bs5 = *(const float2*)&b5[c], bs3 = *(const float2*)&b3[c];
    float bsx = bs7.x + bs5.x + bs3.x, bsy = bs7.y + bs5.y + bs3.y;
    float2 acc[4];
#pragma unroll
    for (int o = 0; o < 4; ++o) {
        float2 idv = *(const float2*)&feat[(size_t)((ty0 + yb0 + o) * 128 + tx0 + xo) * DIMF + c];
        acc[o].x = idv.x + bsx;
        acc[o].y = idv.y + bsy;
    }
    int c2 = cgi << 1;
#pragma unroll
    for (int kx = 0; kx < 7; ++kx) {
        float2 wc[7];
#pragma unroll
        for (int j = 0; j < 7; ++j) wc[j] = b2f(&ws7[j * 7 + kx][c2]);
#pragma unroll
        for (int r = 0; r < 10; ++r) {
            float2 v = b2f(&tile[(yb0 + r) * 14 + xo + kx][c2]);
#pragma unroll
            for (int o = 0; o < 4; ++o) {
                int ky = r - o;
                if (ky >= 0 && ky < 7) {
                    acc[o].x += wc[ky].x * v.x; acc[o].y += wc[ky].y * v.y;
                }
            }
        }
    }
#pragma unroll
    for (int kx = 0; kx < 5; ++kx) {
        float2 wc[5];
#pragma unroll
        for (int j = 0; j < 5; ++j) wc[j] = b2f(&ws5[j * 5 + kx][c2]);
#pragma unroll
        for (int r = 0; r < 8; ++r) {
            float2 v = b2f(&tile[(yb0 + 1 + r) * 14 + xo + 1 + kx][c2]);
#pragma unroll
            for (int o = 0; o < 4; ++o) {
                int ky = r - o;
                if (ky >= 0 && ky < 5) {
                    acc[o].x += wc[ky].x * v.x; acc[o].y += wc[ky].y * v.y;
                }
            }
        }
    }
#pragma unroll
    for (int kx = 0; kx < 3; ++kx) {
        float2 wc[3];
#pragma unroll
        for (int j = 0; j < 3; ++j) wc[j] = b2f(&ws3[j * 3 + kx][c2]);
#pragma unroll
        for (int r = 0; r < 6; ++r) {
            float2 v = b2f(&tile[(yb0 + 2 + r) * 14 + xo + 2 + kx][c2]);
#pragma unroll
            for (int o = 0; o < 4; ++o) {
                int ky = r - o;
                if (ky >= 0 && ky < 3) {
                    acc[o].x += wc[ky].x * v.x; acc[o].y += wc[ky].y * v.y;
                }
            }
        }
    }
#pragma unroll
    for (int o = 0; o < 4; ++o)
        *(float2*)&outfeat[(size_t)((ty0 + yb0 + o) * 128 + tx0 + xo) * DIMF + c] = acc[o];
}

// ---------------- final LN(row0) + 2-class head + softmax + argmax
__global__ __launch_bounds__(64) void head_k(const float* __restrict__ x,
    const float* __restrict__ g, const float* __restrict__ b,
    const float* __restrict__ w, const float* __restrict__ bias, float* __restrict__ out)
{
    int lane = threadIdx.x;
    float v[8], s = 0.f;
#pragma unroll
    for (int i = 0; i < 8; ++i) { v[i] = x[i * 64 + lane]; s += v[i]; }
#pragma unroll
    for (int off = 32; off; off >>= 1) s += __shfl_xor(s, off);
    float mu = s * (1.f / 512.f);
    float vs = 0.f;
#pragma unroll
    for (int i = 0; i < 8; ++i) { float d = v[i] - mu; vs += d * d; }
#pragma unroll
    for (int off = 32; off; off >>= 1) vs += __shfl_xor(vs, off);
    float rstd = rsqrtf(vs * (1.f / 512.f) + 1e-5f);
    float l0 = 0.f, l1 = 0.f;
#pragma unroll
    for (int i = 0; i < 8; ++i) {
        int d = i * 64 + lane;
        float hn = (v[i] - mu) * rstd * g[d] + b[d];
        l0 += hn * w[d * 2];
        l1 += hn * w[d * 2 + 1];
    }
#pragma unroll
    for (int off = 32; off; off >>= 1) { l0 += __shfl_xor(l0, off); l1 += __shfl_xor(l1, off); }
    if (lane == 0) {
        l0 += bias[0]; l1 += bias[1];
        float m = fmaxf(l0, l1);
        float e0 = __expf(l0 - m), e1 = __expf(l1 - m);
        float ss = e0 + e1;
        out[0] = l0; out[1] = l1;
        out[2] = e0 / ss; out[3] = e1 / ss;
        out[4] = (l1 > l0) ? 1.f : 0.f;
    }
}

extern "C" void kernel_launch(void* const* d_in, const int* in_sizes, int n_in,
                              void* d_out, int out_size, void* d_ws, size_t ws_size,
                              hipStream_t stream)
{
    (void)in_sizes; (void)n_in; (void)out_size; (void)ws_size;
    const float* data   = (const float*)d_in[0];
    const float* fc1_w  = (const float*)d_in[1];
    const float* fc1_b  = (const float*)d_in[2];
    const float* cls    = (const float*)d_in[3];
    const float* l1_ng  = (const float*)d_in[4];
    const float* l1_nb  = (const float*)d_in[5];
    const float* l1_qkv = (const float*)d_in[6];
    const float* l1_ow  = (const float*)d_in[7];
    const float* l1_ob  = (const float*)d_in[8];
    const float* l1_rw  = (const float*)d_in[9];
    const float* l2_ng  = (const float*)d_in[10];
    const float* l2_nb  = (const float*)d_in[11];
    const float* l2_qkv = (const float*)d_in[12];
    const float* l2_ow  = (const float*)d_in[13];
    const float* l2_ob  = (const float*)d_in[14];
    const float* l2_rw  = (const float*)d_in[15];
    const float* p_w7   = (const float*)d_in[16];
    const float* p_b7   = (const float*)d_in[17];
    const float* p_w5   = (const float*)d_in[18];
    const float* p_b5   = (const float*)d_in[19];
    const float* p_w3   = (const float*)d_in[20];
    const float* p_b3   = (const float*)d_in[21];
    const float* n_g    = (const float*)d_in[22];
    const float* n_b    = (const float*)d_in[23];
    const float* fc2_w  = (const float*)d_in[24];
    const float* fc2_b  = (const float*)d_in[25];

    char* base = (char*)d_ws;
    auto carve = [&](size_t bytes) { char* p = base; base += (bytes + 255) & ~(size_t)255; return p; };
    float* x               = (float*)carve((size_t)NT * DIMF * 4);
    float* x2              = (float*)carve((size_t)NT * DIMF * 4);
    __hip_bfloat16* xp16   = (__hip_bfloat16*)carve((size_t)NP * DIMF * 2);   // alias: obuf2
    __hip_bfloat16* qkvb16 = (__hip_bfloat16*)carve((size_t)NP * QKVW * 2);   // alias: data16
    __hip_bfloat16* vT16   = (__hip_bfloat16*)carve((size_t)NHEAD * DH * NP * 2);
    __hip_bfloat16* obuf16 = (__hip_bfloat16*)carve((size_t)NP * DIMF * 2);
    __hip_bfloat16* wT     = (__hip_bfloat16*)carve((size_t)QKVW * DIMF * 2);
    float* ql              = (float*)carve(131072 * 4);
    float* kl              = (float*)carve(131072 * 4);
    __hip_bfloat16* ql16   = (__hip_bfloat16*)carve(131072 * 2);
    __hip_bfloat16* kl16   = (__hip_bfloat16*)carve(131072 * 2);
    __hip_bfloat16* wmT16  = (__hip_bfloat16*)carve(131072 * 2);
    float* a2              = (float*)carve(524288 * 4);
    __hip_bfloat16* a2_16  = (__hip_bfloat16*)carve(524288 * 2);
    __hip_bfloat16* zrA    = (__hip_bfloat16*)carve(524288 * 2);
    __hip_bfloat16* zrB    = (__hip_bfloat16*)carve(524288 * 2);
    __hip_bfloat16* ztA    = (__hip_bfloat16*)carve(524288 * 2);
    __hip_bfloat16* ztB    = (__hip_bfloat16*)carve(524288 * 2);
    __hip_bfloat16* xz16   = (__hip_bfloat16*)carve(524288 * 2);
    __hip_bfloat16* t1T16  = (__hip_bfloat16*)carve(524288 * 2);
    __hip_bfloat16* a3vT16 = (__hip_bfloat16*)carve(131072 * 2);
    float* opart = (float*)carve((size_t)64 * A3V_TC * 2048 * 4);
    float* mpart = (float*)carve((size_t)64 * A3V_TC * 32 * 4);
    float* lpart = (float*)carve((size_t)64 * A3V_TC * 32 * 4);
    __hip_bfloat16* obuf2  = xp16;
    __hip_bfloat16* data16 = qkvb16;

    // ---- stem
    cvt_k<<<(16384 * 1024 / 4 + 255) / 256, 256, 0, stream>>>(
        (const float4*)data, (ushort4*)data16, 16384 * 1024 / 4);
    transcvt_k<<<(DIMF / 32) * (1024 / 32), 256, 0, stream>>>(fc1_w, wT, 1024, DIMF);
    gemm_bf16_k<<<dim3(DIMF / 128, 16384 / 128), 256, 0, stream>>>(
        data16, wT, fc1_b, nullptr, x + DIMF, nullptr, 16384, DIMF, 1024, 16384, 1);
    hipMemcpyAsync(x, cls, DIMF * sizeof(float), hipMemcpyDeviceToDevice, stream);

    auto layer = [&](float* xv, const float* ng, const float* nb, const float* qw,
                     const float* ow, const float* ob, const float* rw) {
        hipMemsetAsync(xp16, 0, (size_t)PADR * DIMF * 2, stream);
        ln_k<<<NT, 64, 0, stream>>>(xv, ng, nb, xp16 + (size_t)PADR * DIMF, NT);
        transcvt_k<<<(QKVW / 32) * (DIMF / 32), 256, 0, stream>>>(qw, wT, DIMF, QKVW);
        gemm_bf16_k<<<dim3(QKVW / 128, NP / 128), 256, 0, stream>>>(
            xp16, wT, nullptr, nullptr, nullptr, qkvb16, NP, QKVW, DIMF, NP, 0);
        vtrans_k<<<dim3(NP / 64, NHEAD), 256, 0, stream>>>(qkvb16, vT16);
        landmark_k<<<NHEAD * NLM, 256, 0, stream>>>(qkvb16, ql, kl, ql16, kl16);
        a2_k<<<NHEAD * NLM, 256, 0, stream>>>(ql, kl, a2, a2_16);
        zinit_k<<<NHEAD, 256, 0, stream>>>(a2, zrA, ztA);
        __hip_bfloat16 *zr = zrA, *zt = ztA, *zrN = zrB, *ztN = ztB;
        for (int it = 0; it < 6; ++it) {
            pgemm1_k<<<dim3(4, NHEAD), 256, 0, stream>>>(a2_16, zt, xz16, t1T16);
            pgemm3_k<<<dim3(4, NHEAD), 256, 0, stream>>>(xz16, t1T16, zr, zrN, ztN);
            __hip_bfloat16* t;
            t = zr; zr = zrN; zrN = t;
            t = zt; zt = ztN; ztN = t;
        }
        a3v_flash_k<<<dim3(32, A3V_TC), 128, 0, stream>>>(ql16, qkvb16, vT16, opart, mpart, lpart);
        a3v_comb_k<<<64, 64, 0, stream>>>(opart, mpart, lpart, a3vT16);
        wm_k<<<NHEAD, 256, 0, stream>>>(zr, a3vT16, wmT16);
        attnout_mfma_k<<<dim3(NP / 64, NHEAD), 128, 0, stream>>>(qkvb16, kl16, wmT16, obuf16);
        resconv_tile_k<<<dim3(NP / 128, NHEAD), 256, 0, stream>>>(qkvb16, rw, obuf16, obuf2);
        transcvt_k<<<(DIMF / 32) * (DIMF / 32), 256, 0, stream>>>(ow, wT, DIMF, DIMF);
        gemm_bf16_k<<<dim3(DIMF / 128, (NT + 127) / 128), 256, 0, stream>>>(
            obuf2 + (size_t)PADR * DIMF, wT, ob, xv, xv, nullptr, NT, DIMF, DIMF, NT, 0);
    };

    layer(x, l1_ng, l1_nb, l1_qkv, l1_ow, l1_ob, l1_rw);

    ppeg3_k<<<dim3(256, 16), 256, 0, stream>>>(x, p_w7, p_b7, p_w5, p_b5, p_w3, p_b3, x2 + DIMF);
    hipMemcpyAsync(x2, x, DIMF * sizeof(float), hipMemcpyDeviceToDevice, stream);

    layer(x2, l2_ng, l2_nb, l2_qkv, l2_ow, l2_ob, l2_rw);

    head_k<<<1, 64, 0, stream>>>(x2, n_g, n_b, fc2_w, fc2_b, (float*)d_out);
}

// Round 11
// 1351.844 us; speedup vs baseline: 1.1635x; 1.0443x over previous
//
#include <hip/hip_runtime.h>
#include <hip/hip_bf16.h>

// TransMIL forward. Round 11: revert XCD swizzle (proven net-negative for these
// latency-bound short-K GEMMs despite 2.6x FETCH reduction); round-7 GEMM +
// bf16 attn-out path; ln_k absorbs the pad memset.

#define NT 16385
#define NP 16640
#define PADR 255
#define DIMF 512
#define QKVW 1536
#define NHEAD 8
#define DH 64
#define NLM 256
#define LSEG 65
#define A3V_TC 20

typedef short bf16x8 __attribute__((ext_vector_type(8)));
typedef short bf16x4 __attribute__((ext_vector_type(4)));
typedef float f32x4 __attribute__((ext_vector_type(4)));

__device__ __forceinline__ void gload_lds16(const void* g, void* l) {
    __builtin_amdgcn_global_load_lds(
        (const __attribute__((address_space(1))) void*)g,
        (__attribute__((address_space(3))) void*)l, 16, 0, 0);
}

__device__ __forceinline__ float2 b2f(const __hip_bfloat16* p) {
    ushort2 u = *(const ushort2*)p;
    float2 r;
    r.x = __uint_as_float((unsigned)u.x << 16);
    r.y = __uint_as_float((unsigned)u.y << 16);
    return r;
}

__device__ __forceinline__ unsigned f2b16(float a, float b) {
    union { unsigned u; __hip_bfloat16 h[2]; } c;
    c.h[0] = __float2bfloat16(a); c.h[1] = __float2bfloat16(b);
    return c.u;
}

__device__ __forceinline__ bf16x4 f4b(float a, float b, float c, float d) {
    union { bf16x4 v; __hip_bfloat16 h[4]; } u;
    u.h[0] = __float2bfloat16(a); u.h[1] = __float2bfloat16(b);
    u.h[2] = __float2bfloat16(c); u.h[3] = __float2bfloat16(d);
    return u.v;
}

// ---------------- bf16 MFMA GEMM (single-buffer 32KB LDS, identity block map)
// C = A[MxK]@BT[NxK]^T + bias (+Cacc)(+relu); fp32 C or bf16 C16.
__global__ __launch_bounds__(256) void gemm_bf16_k(
    const __hip_bfloat16* __restrict__ A, const __hip_bfloat16* __restrict__ BT,
    const float* __restrict__ bias, const float* __restrict__ Cacc,
    float* __restrict__ C, __hip_bfloat16* __restrict__ C16,
    int M, int N, int K, int MA, int relu)
{
    __shared__ __align__(16) __hip_bfloat16 Asl[128 * 64];
    __shared__ __align__(16) __hip_bfloat16 Bsl[128 * 64];
    int tid = threadIdx.x;
    int wid = tid >> 6, lane = tid & 63;
    int m0 = blockIdx.y << 7, n0 = blockIdx.x << 7;
    int wr = (wid >> 1) << 6, wc = (wid & 1) << 6;
    f32x4 acc[4][4] = {};
    int lr = lane >> 3, lk = (lane & 7) << 3;
    for (int kt = 0; kt < K; kt += 64) {
#pragma unroll
        for (int i = 0; i < 4; ++i) {
            int ch = wid * 4 + i;
            int rowA = m0 + ch * 8 + lr;
            rowA = rowA < MA ? rowA : (MA - 1);
            gload_lds16(A + (size_t)rowA * K + kt + lk, &Asl[ch * 512]);
            int rowB = n0 + ch * 8 + lr;
            gload_lds16(BT + (size_t)rowB * K + kt + lk, &Bsl[ch * 512]);
        }
        __syncthreads();
#pragma unroll
        for (int ks = 0; ks < 2; ++ks) {
            int kb = ks * 32 + (lane >> 4) * 8;
            bf16x8 af[4], bfr[4];
#pragma unroll
            for (int m = 0; m < 4; ++m)
                af[m] = *(const bf16x8*)&Asl[(wr + m * 16 + (lane & 15)) * 64 + kb];
#pragma unroll
            for (int n = 0; n < 4; ++n)
                bfr[n] = *(const bf16x8*)&Bsl[(wc + n * 16 + (lane & 15)) * 64 + kb];
#pragma unroll
            for (int m = 0; m < 4; ++m)
#pragma unroll
                for (int n = 0; n < 4; ++n)
                    acc[m][n] = __builtin_amdgcn_mfma_f32_16x16x32_bf16(
                        af[m], bfr[n], acc[m][n], 0, 0, 0);
        }
        __syncthreads();
    }
    int cr = (lane >> 4) << 2, cc = lane & 15;
#pragma unroll
    for (int m = 0; m < 4; ++m) {
#pragma unroll
        for (int i = 0; i < 4; ++i) {
            int gm = m0 + wr + m * 16 + cr + i;
            if (gm >= M) continue;
#pragma unroll
            for (int n = 0; n < 4; ++n) {
                int gn = n0 + wc + n * 16 + cc;
                float v = acc[m][n][i];
                if (bias) v += bias[gn];
                if (Cacc) v += Cacc[(size_t)gm * N + gn];
                if (relu) v = fmaxf(v, 0.f);
                if (C16) C16[(size_t)gm * N + gn] = __float2bfloat16(v);
                else C[(size_t)gm * N + gn] = v;
            }
        }
    }
}

// ---------------- fp32 [KxN] -> bf16 [NxK] tiled transpose-convert
__global__ __launch_bounds__(256) void transcvt_k(const float* __restrict__ W,
    __hip_bfloat16* __restrict__ WT, int K, int N)
{
    __shared__ float t[32][33];
    int nt = N >> 5;
    int n0 = (blockIdx.x % nt) << 5, k0 = (blockIdx.x / nt) << 5;
    int tx = threadIdx.x & 31, ty = threadIdx.x >> 5;
    for (int r = ty; r < 32; r += 8) t[r][tx] = W[(size_t)(k0 + r) * N + n0 + tx];
    __syncthreads();
    for (int r = ty; r < 32; r += 8)
        WT[(size_t)(n0 + r) * K + k0 + tx] = __float2bfloat16(t[tx][r]);
}

// ---------------- fp32 -> bf16 convert (vectorized)
__global__ __launch_bounds__(256) void cvt_k(const float4* __restrict__ in,
    ushort4* __restrict__ out, int n4)
{
    int i = blockIdx.x * 256 + threadIdx.x;
    if (i >= n4) return;
    float4 v = in[i];
    union { __hip_bfloat16 h[4]; ushort4 u; } cv;
    cv.h[0] = __float2bfloat16(v.x); cv.h[1] = __float2bfloat16(v.y);
    cv.h[2] = __float2bfloat16(v.z); cv.h[3] = __float2bfloat16(v.w);
    out[i] = cv.u;
}

// ---------------- v transpose: vT16[h][d][t]
__global__ __launch_bounds__(256) void vtrans_k(const __hip_bfloat16* __restrict__ qkvb16,
    __hip_bfloat16* __restrict__ vT16)
{
    int h = blockIdx.y;
    int t0 = blockIdx.x << 6;
    __shared__ float tile[64][65];
    int tid = threadIdx.x;
    for (int e = tid; e < 512; e += 256) {
        int r = e >> 3, c8 = (e & 7) << 3;
        union { bf16x8 v; __hip_bfloat16 hh[8]; } u;
        u.v = *(const bf16x8*)(qkvb16 + (size_t)(t0 + r) * QKVW + 1024 + (h << 6) + c8);
#pragma unroll
        for (int j = 0; j < 8; ++j) tile[r][c8 + j] = __bfloat162float(u.hh[j]);
    }
    __syncthreads();
    for (int e = tid; e < 512; e += 256) {
        int d = e >> 3, t8 = (e & 7) << 3;
        union { bf16x8 v; __hip_bfloat16 hh[8]; } u;
#pragma unroll
        for (int j = 0; j < 8; ++j) u.hh[j] = __float2bfloat16(tile[t8 + j][d]);
        *(bf16x8*)(vT16 + ((size_t)(h << 6) + d) * NP + t0 + t8) = u.v;
    }
}

// ---------------- LayerNorm per row (512) -> bf16; rows<PADR write zeros (pad)
__global__ __launch_bounds__(64) void ln_k(const float* __restrict__ in,
    const float* __restrict__ g, const float* __restrict__ b,
    __hip_bfloat16* __restrict__ out)
{
    int r = blockIdx.x;
    int lane = threadIdx.x;
    __hip_bfloat16* orow = out + (size_t)r * DIMF;
    if (r < PADR) {
        ushort4 z = make_ushort4(0, 0, 0, 0);
#pragma unroll
        for (int i = 0; i < 2; ++i)
            *(ushort4*)&orow[(i * 64 + lane) * 4] = z;
        return;
    }
    const float* xr = in + (size_t)(r - PADR) * DIMF;
    float v[8], s = 0.f;
#pragma unroll
    for (int i = 0; i < 8; ++i) { v[i] = xr[i * 64 + lane]; s += v[i]; }
#pragma unroll
    for (int off = 32; off; off >>= 1) s += __shfl_xor(s, off);
    float mu = s * (1.f / 512.f);
    float vs = 0.f;
#pragma unroll
    for (int i = 0; i < 8; ++i) { float d = v[i] - mu; vs += d * d; }
#pragma unroll
    for (int off = 32; off; off >>= 1) vs += __shfl_xor(vs, off);
    float rstd = rsqrtf(vs * (1.f / 512.f) + 1e-5f);
#pragma unroll
    for (int i = 0; i < 8; ++i) {
        int d = i * 64 + lane;
        orow[d] = __float2bfloat16((v[i] - mu) * rstd * g[d] + b[d]);
    }
}

// ---------------- landmark means, 4 waves split the 65-row sum
__global__ __launch_bounds__(256) void landmark_k(const __hip_bfloat16* __restrict__ qkvb16,
    float* __restrict__ ql, float* __restrict__ kl,
    __hip_bfloat16* __restrict__ ql16, __hip_bfloat16* __restrict__ kl16)
{
    int bx = blockIdx.x;
    int h = bx >> 8, j = bx & 255;
    int w = threadIdx.x >> 6, d = threadIdx.x & 63;
    __shared__ float pq[4][64], pk[4][64];
    float qs = 0.f, ks = 0.f;
    for (int u = w; u < LSEG; u += 4) {
        size_t addr = (size_t)(j * LSEG + u) * QKVW + (h << 6) + d;
        qs += __bfloat162float(qkvb16[addr]);
        ks += __bfloat162float(qkvb16[addr + 512]);
    }
    pq[w][d] = qs; pk[w][d] = ks;
    __syncthreads();
    if (threadIdx.x < 64) {
        float q = pq[0][d] + pq[1][d] + pq[2][d] + pq[3][d];
        float k = pk[0][d] + pk[1][d] + pk[2][d] + pk[3][d];
        float qm = q * (1.f / 65.f) * 0.125f;
        float km = k * (1.f / 65.f);
        ql[(size_t)bx * 64 + d] = qm;
        kl[(size_t)bx * 64 + d] = km;
        ql16[(size_t)bx * 64 + d] = __float2bfloat16(qm);
        kl16[(size_t)bx * 64 + d] = __float2bfloat16(km);
    }
}

// ---------------- a2 = softmax(q_l @ k_l^T); writes fp32 + bf16 row-major
__global__ __launch_bounds__(256) void a2_k(const float* __restrict__ ql,
    const float* __restrict__ kl, float* __restrict__ a2, __hip_bfloat16* __restrict__ a2_16)
{
    int h = blockIdx.x >> 8, i = blockIdx.x & 255;
    int j = threadIdx.x;
    __shared__ float qs[64];
    __shared__ float red[256];
    if (j < 64) qs[j] = ql[((size_t)(h << 8) + i) * 64 + j];
    __syncthreads();
    const float* kr = kl + ((size_t)(h << 8) + j) * 64;
    float s = 0.f;
#pragma unroll 8
    for (int d = 0; d < 64; ++d) s += qs[d] * kr[d];
    red[j] = s; __syncthreads();
    for (int st = 128; st; st >>= 1) { if (j < st) red[j] = fmaxf(red[j], red[j + st]); __syncthreads(); }
    float mx = red[0]; __syncthreads();
    float p = __expf(s - mx);
    red[j] = p; __syncthreads();
    for (int st = 128; st; st >>= 1) { if (j < st) red[j] += red[j + st]; __syncthreads(); }
    float v = p / red[0];
    a2[((size_t)h << 16) + i * 256 + j] = v;
    a2_16[((size_t)h << 16) + i * 256 + j] = __float2bfloat16(v);
}

// ---------------- pinv init: z = a2^T/(maxrow*maxcol); LDS-tiled transpose
__global__ __launch_bounds__(256) void zinit_k(const float* __restrict__ a2,
    __hip_bfloat16* __restrict__ zr16, __hip_bfloat16* __restrict__ zT16)
{
    int h = blockIdx.x, t = threadIdx.x;
    const float* X = a2 + ((size_t)h << 16);
    __shared__ float red[256];
    __shared__ float tl[64][65];
    float rs = 0.f;
    const float4* Xr = (const float4*)(X + (size_t)t * 256);
    for (int j = 0; j < 64; ++j) {
        float4 v = Xr[j];
        rs += fabsf(v.x) + fabsf(v.y) + fabsf(v.z) + fabsf(v.w);
    }
    red[t] = rs; __syncthreads();
    for (int st = 128; st; st >>= 1) { if (t < st) red[t] = fmaxf(red[t], red[t + st]); __syncthreads(); }
    float colv = red[0]; __syncthreads();
    float cs = 0.f;
    for (int i = 0; i < 256; ++i) cs += fabsf(X[i * 256 + t]);
    red[t] = cs; __syncthreads();
    for (int st = 128; st; st >>= 1) { if (t < st) red[t] = fmaxf(red[t], red[t + st]); __syncthreads(); }
    float rowv = red[0];
    float inv = 1.f / (colv * rowv);
    int cl = t & 63, rg = t >> 6;
    for (int tr = 0; tr < 4; ++tr)
        for (int tc = 0; tc < 4; ++tc) {
            __syncthreads();
#pragma unroll
            for (int k = 0; k < 16; ++k) {
                int rl = (k << 2) + rg;
                tl[rl][cl] = X[(size_t)(tr * 64 + rl) * 256 + tc * 64 + cl];
            }
            __syncthreads();
#pragma unroll
            for (int k = 0; k < 16; ++k) {
                int rl = (k << 2) + rg;
                zT16[((size_t)h << 16) + (size_t)(tr * 64 + rl) * 256 + tc * 64 + cl] =
                    __float2bfloat16(tl[rl][cl] * inv);
                zr16[((size_t)h << 16) + (size_t)(tc * 64 + rl) * 256 + tr * 64 + cl] =
                    __float2bfloat16(tl[cl][rl] * inv);
            }
        }
}

// ---------------- pinv G1: xz = a2 @ Z. Writes xz16 + t1T16=7I-xz^T.
__global__ __launch_bounds__(256) void pgemm1_k(
    const __hip_bfloat16* __restrict__ a2_16, const __hip_bfloat16* __restrict__ zT16,
    __hip_bfloat16* __restrict__ xz16, __hip_bfloat16* __restrict__ t1T16)
{
    int h = blockIdx.y, n0 = blockIdx.x << 6;
    int lane = threadIdx.x & 63;
    int r0 = (threadIdx.x >> 6) << 6;
    int rA = lane & 15, g = lane >> 4, kp = g << 3;
    const __hip_bfloat16* Ah = a2_16 + ((size_t)h << 16);
    const __hip_bfloat16* Bh = zT16 + ((size_t)h << 16);
    f32x4 acc[4][4] = {};
    for (int ks = 0; ks < 8; ++ks) {
        bf16x8 af[4], bfr[4];
#pragma unroll
        for (int m = 0; m < 4; ++m)
            af[m] = *(const bf16x8*)&Ah[(size_t)(r0 + m * 16 + rA) * 256 + ks * 32 + kp];
#pragma unroll
        for (int n = 0; n < 4; ++n)
            bfr[n] = *(const bf16x8*)&Bh[(size_t)(n0 + n * 16 + rA) * 256 + ks * 32 + kp];
#pragma unroll
        for (int m = 0; m < 4; ++m)
#pragma unroll
            for (int n = 0; n < 4; ++n)
                acc[m][n] = __builtin_amdgcn_mfma_f32_16x16x32_bf16(af[m], bfr[n], acc[m][n], 0, 0, 0);
    }
    __hip_bfloat16* xzh = xz16 + ((size_t)h << 16);
    __hip_bfloat16* t1h = t1T16 + ((size_t)h << 16);
#pragma unroll
    for (int m = 0; m < 4; ++m)
#pragma unroll
        for (int i = 0; i < 4; ++i) {
            int gr = r0 + m * 16 + (g << 2) + i;
#pragma unroll
            for (int n = 0; n < 4; ++n) {
                int gc = n0 + n * 16 + rA;
                float v = acc[m][n][i];
                xzh[(size_t)gr * 256 + gc] = __float2bfloat16(v);
                t1h[(size_t)gc * 256 + gr] = __float2bfloat16((gr == gc ? 7.f : 0.f) - v);
            }
        }
}

// ---------------- pinv G2+G3+G4 fused per column-stripe
__global__ __launch_bounds__(256) void pgemm3_k(
    const __hip_bfloat16* __restrict__ xz16, const __hip_bfloat16* __restrict__ t1T16,
    const __hip_bfloat16* __restrict__ zr16,
    __hip_bfloat16* __restrict__ znr16, __hip_bfloat16* __restrict__ znT16)
{
    __shared__ __align__(16) __hip_bfloat16 tA[64][264];
    __shared__ __align__(16) __hip_bfloat16 tB[64][264];
    int h = blockIdx.y, n0 = blockIdx.x << 6;
    int lane = threadIdx.x & 63;
    int r0 = (threadIdx.x >> 6) << 6;
    int rA = lane & 15, g = lane >> 4, kp = g << 3;
    const __hip_bfloat16* Xh = xz16 + ((size_t)h << 16);
    const __hip_bfloat16* T1h = t1T16 + ((size_t)h << 16);
    {
        f32x4 acc[4][4] = {};
        for (int ks = 0; ks < 8; ++ks) {
            bf16x8 af[4], bfr[4];
#pragma unroll
            for (int m = 0; m < 4; ++m)
                af[m] = *(const bf16x8*)&Xh[(size_t)(r0 + m * 16 + rA) * 256 + ks * 32 + kp];
#pragma unroll
            for (int n = 0; n < 4; ++n)
                bfr[n] = *(const bf16x8*)&T1h[(size_t)(n0 + n * 16 + rA) * 256 + ks * 32 + kp];
#pragma unroll
            for (int m = 0; m < 4; ++m)
#pragma unroll
                for (int n = 0; n < 4; ++n)
                    acc[m][n] = __builtin_amdgcn_mfma_f32_16x16x32_bf16(af[m], bfr[n], acc[m][n], 0, 0, 0);
        }
#pragma unroll
        for (int m = 0; m < 4; ++m)
#pragma unroll
            for (int n = 0; n < 4; ++n) {
                int gr0 = r0 + m * 16 + (g << 2);
                int cl = n * 16 + rA;
                *(bf16x4*)&tA[cl][gr0] = f4b(
                    ((gr0 + 0 == n0 + cl) ? 15.f : 0.f) - acc[m][n][0],
                    ((gr0 + 1 == n0 + cl) ? 15.f : 0.f) - acc[m][n][1],
                    ((gr0 + 2 == n0 + cl) ? 15.f : 0.f) - acc[m][n][2],
                    ((gr0 + 3 == n0 + cl) ? 15.f : 0.f) - acc[m][n][3]);
            }
    }
    __syncthreads();
    {
        f32x4 acc[4][4] = {};
        for (int ks = 0; ks < 8; ++ks) {
            bf16x8 af[4], bfr[4];
#pragma unroll
            for (int m = 0; m < 4; ++m)
                af[m] = *(const bf16x8*)&Xh[(size_t)(r0 + m * 16 + rA) * 256 + ks * 32 + kp];
#pragma unroll
            for (int n = 0; n < 4; ++n)
                bfr[n] = *(const bf16x8*)&tA[n * 16 + rA][ks * 32 + kp];
#pragma unroll
            for (int m = 0; m < 4; ++m)
#pragma unroll
                for (int n = 0; n < 4; ++n)
                    acc[m][n] = __builtin_amdgcn_mfma_f32_16x16x32_bf16(af[m], bfr[n], acc[m][n], 0, 0, 0);
        }
#pragma unroll
        for (int m = 0; m < 4; ++m)
#pragma unroll
            for (int n = 0; n < 4; ++n) {
                int gr0 = r0 + m * 16 + (g << 2);
                int cl = n * 16 + rA;
                *(bf16x4*)&tB[cl][gr0] = f4b(
                    ((gr0 + 0 == n0 + cl) ? 13.f : 0.f) - acc[m][n][0],
                    ((gr0 + 1 == n0 + cl) ? 13.f : 0.f) - acc[m][n][1],
                    ((gr0 + 2 == n0 + cl) ? 13.f : 0.f) - acc[m][n][2],
                    ((gr0 + 3 == n0 + cl) ? 13.f : 0.f) - acc[m][n][3]);
            }
    }
    __syncthreads();
    {
        const __hip_bfloat16* Zh = zr16 + ((size_t)h << 16);
        f32x4 acc[4][4] = {};
        for (int ks = 0; ks < 8; ++ks) {
            bf16x8 af[4], bfr[4];
#pragma unroll
            for (int m = 0; m < 4; ++m)
                af[m] = *(const bf16x8*)&Zh[(size_t)(r0 + m * 16 + rA) * 256 + ks * 32 + kp];
#pragma unroll
            for (int n = 0; n < 4; ++n)
                bfr[n] = *(const bf16x8*)&tB[n * 16 + rA][ks * 32 + kp];
#pragma unroll
            for (int m = 0; m < 4; ++m)
#pragma unroll
                for (int n = 0; n < 4; ++n)
                    acc[m][n] = __builtin_amdgcn_mfma_f32_16x16x32_bf16(af[m], bfr[n], acc[m][n], 0, 0, 0);
        }
        __hip_bfloat16* zrh = znr16 + ((size_t)h << 16);
        __hip_bfloat16* zth = znT16 + ((size_t)h << 16);
#pragma unroll
        for (int m = 0; m < 4; ++m)
#pragma unroll
            for (int i = 0; i < 4; ++i) {
                int gr = r0 + m * 16 + (g << 2) + i;
#pragma unroll
                for (int n = 0; n < 4; ++n) {
                    int gc = n0 + n * 16 + rA;
                    float v = 0.25f * acc[m][n][i];
                    zrh[(size_t)gr * 256 + gc] = __float2bfloat16(v);
                    zth[(size_t)gc * 256 + gr] = __float2bfloat16(v);
                }
            }
    }
}

// ---------------- wm = Zfinal @ a3v -> wmT16
__global__ __launch_bounds__(256) void wm_k(
    const __hip_bfloat16* __restrict__ zr16, const __hip_bfloat16* __restrict__ a3vT16,
    __hip_bfloat16* __restrict__ wmT16)
{
    int h = blockIdx.x;
    int lane = threadIdx.x & 63;
    int r0 = (threadIdx.x >> 6) << 6;
    int rA = lane & 15, g = lane >> 4, kp = g << 3;
    const __hip_bfloat16* Zh = zr16 + ((size_t)h << 16);
    const __hip_bfloat16* Bh = a3vT16 + ((size_t)h << 14);
    f32x4 acc[4][4] = {};
    for (int ks = 0; ks < 8; ++ks) {
        bf16x8 af[4], bfr[4];
#pragma unroll
        for (int m = 0; m < 4; ++m)
            af[m] = *(const bf16x8*)&Zh[(size_t)(r0 + m * 16 + rA) * 256 + ks * 32 + kp];
#pragma unroll
        for (int n = 0; n < 4; ++n)
            bfr[n] = *(const bf16x8*)&Bh[(size_t)(n * 16 + rA) * 256 + ks * 32 + kp];
#pragma unroll
        for (int m = 0; m < 4; ++m)
#pragma unroll
            for (int n = 0; n < 4; ++n)
                acc[m][n] = __builtin_amdgcn_mfma_f32_16x16x32_bf16(af[m], bfr[n], acc[m][n], 0, 0, 0);
    }
    __hip_bfloat16* Wh = wmT16 + ((size_t)h << 14);
#pragma unroll
    for (int m = 0; m < 4; ++m)
#pragma unroll
        for (int i = 0; i < 4; ++i) {
            int gr = r0 + m * 16 + (g << 2) + i;
#pragma unroll
            for (int n = 0; n < 4; ++n)
                Wh[(size_t)(n * 16 + rA) * 256 + gr] = __float2bfloat16(acc[m][n][i]);
        }
}

// ---------------- MFMA flash a3v partials
__global__ __launch_bounds__(128) void a3v_flash_k(
    const __hip_bfloat16* __restrict__ ql16, const __hip_bfloat16* __restrict__ qkvb16,
    const __hip_bfloat16* __restrict__ vT16,
    float* __restrict__ opart, float* __restrict__ mpart, float* __restrict__ lpart)
{
    int bx = blockIdx.x;
    int h = bx >> 2, qb = bx & 3;
    int tc = blockIdx.y;
    int wv = threadIdx.x >> 6;
    int lane = threadIdx.x & 63;
    int rA = lane & 15, g = lane >> 4, kp = g << 3;
    __shared__ __align__(16) __hip_bfloat16 Plds[2][32 * 64];
    char* P = (char*)&Plds[wv][0];

    bf16x8 qa[2][2];
    const __hip_bfloat16* qlh = ql16 + ((size_t)h << 14);
#pragma unroll
    for (int m = 0; m < 2; ++m)
#pragma unroll
        for (int ks = 0; ks < 2; ++ks)
            qa[m][ks] = *(const bf16x8*)(qlh +
                (size_t)((qb << 6) + (wv << 5) + (m << 4) + rA) * 64 + ks * 32 + kp);

    const __hip_bfloat16* kg = qkvb16 + 512 + (h << 6);
    const __hip_bfloat16* vg = vT16 + ((size_t)(h << 6)) * NP;

    f32x4 O[2][4] = {};
    float m_[2][4], l_[2][4];
#pragma unroll
    for (int m = 0; m < 2; ++m)
#pragma unroll
        for (int i = 0; i < 4; ++i) { m_[m][i] = -3e38f; l_[m][i] = 0.f; }

    for (int tile = tc * 13; tile < tc * 13 + 13; ++tile) {
        int t0 = tile << 6;
        f32x4 S[2][4] = {};
#pragma unroll
        for (int n = 0; n < 4; ++n)
#pragma unroll
            for (int ks = 0; ks < 2; ++ks) {
                bf16x8 kb = *(const bf16x8*)(kg + (size_t)(t0 + (n << 4) + rA) * QKVW + ks * 32 + kp);
                S[0][n] = __builtin_amdgcn_mfma_f32_16x16x32_bf16(qa[0][ks], kb, S[0][n], 0, 0, 0);
                S[1][n] = __builtin_amdgcn_mfma_f32_16x16x32_bf16(qa[1][ks], kb, S[1][n], 0, 0, 0);
            }
        float f_[2][4];
#pragma unroll
        for (int m = 0; m < 2; ++m)
#pragma unroll
            for (int i = 0; i < 4; ++i) {
                float mx = fmaxf(fmaxf(S[m][0][i], S[m][1][i]), fmaxf(S[m][2][i], S[m][3][i]));
#pragma unroll
                for (int msk = 8; msk; msk >>= 1) mx = fmaxf(mx, __shfl_xor(mx, msk));
                float mn = fmaxf(m_[m][i], mx);
                float f = __expf(m_[m][i] - mn);
                int r = (m << 4) + (g << 2) + i;
                int swz = (r & 7) << 4;
                float sum = 0.f;
#pragma unroll
                for (int n = 0; n < 4; ++n) {
                    float p = __expf(S[m][n][i] - mn);
                    sum += p;
                    int byte = (r << 7) + (((n << 4) + rA) << 1);
                    *(__hip_bfloat16*)(P + (byte ^ swz)) = __float2bfloat16(p);
                }
#pragma unroll
                for (int msk = 8; msk; msk >>= 1) sum += __shfl_xor(sum, msk);
                l_[m][i] = l_[m][i] * f + sum;
                m_[m][i] = mn;
                f_[m][i] = f;
            }
#pragma unroll
        for (int m = 0; m < 2; ++m)
#pragma unroll
            for (int i = 0; i < 4; ++i) {
                float f = f_[m][i];
#pragma unroll
                for (int n = 0; n < 4; ++n) O[m][n][i] *= f;
            }
#pragma unroll
        for (int ks2 = 0; ks2 < 2; ++ks2) {
            bf16x8 pa[2];
#pragma unroll
            for (int m = 0; m < 2; ++m) {
                int rr = (m << 4) + rA;
                int byte = (rr << 7) + ((ks2 * 32 + kp) << 1);
                pa[m] = *(const bf16x8*)(P + (byte ^ ((rr & 7) << 4)));
            }
#pragma unroll
            for (int n = 0; n < 4; ++n) {
                bf16x8 vb = *(const bf16x8*)(vg + (size_t)((n << 4) + rA) * NP + t0 + ks2 * 32 + kp);
                O[0][n] = __builtin_amdgcn_mfma_f32_16x16x32_bf16(pa[0], vb, O[0][n], 0, 0, 0);
                O[1][n] = __builtin_amdgcn_mfma_f32_16x16x32_bf16(pa[1], vb, O[1][n], 0, 0, 0);
            }
        }
    }
    int pb2 = (bx << 1) | wv;
    size_t obase = ((size_t)pb2 * A3V_TC + tc) * 2048;
#pragma unroll
    for (int m = 0; m < 2; ++m)
#pragma unroll
        for (int i = 0; i < 4; ++i) {
            int r = (m << 4) + (g << 2) + i;
#pragma unroll
            for (int n = 0; n < 4; ++n)
                opart[obase + (size_t)r * 64 + (n << 4) + rA] = O[m][n][i];
            if (rA == 0) {
                mpart[((size_t)pb2 * A3V_TC + tc) * 32 + r] = m_[m][i];
                lpart[((size_t)pb2 * A3V_TC + tc) * 32 + r] = l_[m][i];
            }
        }
}

// ---------------- a3v combine -> a3vT16[h][d][j] bf16
__global__ __launch_bounds__(64) void a3v_comb_k(const float* __restrict__ opart,
    const float* __restrict__ mpart, const float* __restrict__ lpart,
    __hip_bfloat16* __restrict__ a3vT16)
{
    int pb = blockIdx.x, d = threadIdx.x;
    int h = pb >> 3;
    for (int r = 0; r < 32; ++r) {
        float M = -3e38f;
        for (int tc = 0; tc < A3V_TC; ++tc)
            M = fmaxf(M, mpart[((size_t)pb * A3V_TC + tc) * 32 + r]);
        float L = 0.f, od = 0.f;
        for (int tc = 0; tc < A3V_TC; ++tc) {
            float w = __expf(mpart[((size_t)pb * A3V_TC + tc) * 32 + r] - M);
            L += lpart[((size_t)pb * A3V_TC + tc) * 32 + r] * w;
            od += w * opart[((size_t)pb * A3V_TC + tc) * 2048 + (size_t)r * 64 + d];
        }
        int j = ((pb & 7) << 5) + r;
        a3vT16[((size_t)((h << 6) + d) << 8) + j] = __float2bfloat16(od / L);
    }
}

// ---------------- MFMA fused sim1-softmax @ Wm -> bf16 out
__global__ __launch_bounds__(128) void attnout_mfma_k(
    const __hip_bfloat16* __restrict__ qkvb16, const __hip_bfloat16* __restrict__ kl16,
    const __hip_bfloat16* __restrict__ wmT16, __hip_bfloat16* __restrict__ o)
{
    int h = blockIdx.y;
    int rbase = (blockIdx.x << 6) + ((threadIdx.x >> 6) << 5);
    int lane = threadIdx.x & 63;
    int rA = lane & 15;
    int g = lane >> 4;
    int kp = g << 3;
    __shared__ __align__(16) __hip_bfloat16 Plds[2][32 * 256];
    char* P = (char*)&Plds[threadIdx.x >> 6][0];

    bf16x8 qa[2][2];
#pragma unroll
    for (int m = 0; m < 2; ++m)
#pragma unroll
        for (int ks = 0; ks < 2; ++ks)
            qa[m][ks] = *(const bf16x8*)(qkvb16 +
                (size_t)(rbase + m * 16 + rA) * QKVW + (h << 6) + ks * 32 + kp);

    const __hip_bfloat16* klh = kl16 + ((size_t)h << 14);
    f32x4 S[2][16] = {};
#pragma unroll
    for (int n = 0; n < 16; ++n) {
#pragma unroll
        for (int ks = 0; ks < 2; ++ks) {
            bf16x8 kb = *(const bf16x8*)(klh + (size_t)((n << 4) + rA) * 64 + ks * 32 + kp);
            S[0][n] = __builtin_amdgcn_mfma_f32_16x16x32_bf16(qa[0][ks], kb, S[0][n], 0, 0, 0);
            S[1][n] = __builtin_amdgcn_mfma_f32_16x16x32_bf16(qa[1][ks], kb, S[1][n], 0, 0, 0);
        }
    }
#pragma unroll
    for (int m = 0; m < 2; ++m)
#pragma unroll
        for (int n = 0; n < 16; ++n) S[m][n] *= 0.125f;

    float lsum[2][4];
#pragma unroll
    for (int m = 0; m < 2; ++m)
#pragma unroll
        for (int i = 0; i < 4; ++i) {
            float mx = -3e38f;
#pragma unroll
            for (int n = 0; n < 16; ++n) mx = fmaxf(mx, S[m][n][i]);
#pragma unroll
            for (int msk = 8; msk; msk >>= 1) mx = fmaxf(mx, __shfl_xor(mx, msk));
            float sum = 0.f;
            int r = (m << 4) + (g << 2) + i;
            int swz = (r & 7) << 4;
#pragma unroll
            for (int n = 0; n < 16; ++n) {
                float p = __expf(S[m][n][i] - mx);
                sum += p;
                int byte = (r << 9) + (((n << 4) + rA) << 1);
                *(__hip_bfloat16*)(P + (byte ^ swz)) = __float2bfloat16(p);
            }
#pragma unroll
            for (int msk = 8; msk; msk >>= 1) sum += __shfl_xor(sum, msk);
            lsum[m][i] = sum;
        }

    const __hip_bfloat16* wmh = wmT16 + ((size_t)h << 14);
    f32x4 O[2][4] = {};
#pragma unroll
    for (int kc = 0; kc < 8; ++kc) {
        bf16x8 pa[2];
#pragma unroll
        for (int m = 0; m < 2; ++m) {
            int rr = (m << 4) + rA;
            int byte = (rr << 9) + (((kc << 5) + kp) << 1);
            pa[m] = *(const bf16x8*)(P + (byte ^ ((rr & 7) << 4)));
        }
#pragma unroll
        for (int n = 0; n < 4; ++n) {
            bf16x8 wb = *(const bf16x8*)(wmh + (size_t)((n << 4) + rA) * 256 + (kc << 5) + kp);
#pragma unroll
            for (int m = 0; m < 2; ++m)
                O[m][n] = __builtin_amdgcn_mfma_f32_16x16x32_bf16(pa[m], wb, O[m][n], 0, 0, 0);
        }
    }
#pragma unroll
    for (int m = 0; m < 2; ++m)
#pragma unroll
        for (int i = 0; i < 4; ++i) {
            float inv = 1.f / lsum[m][i];
            int gm = rbase + (m << 4) + (g << 2) + i;
#pragma unroll
            for (int n = 0; n < 4; ++n)
                o[(size_t)gm * DIMF + (h << 6) + (n << 4) + rA] =
                    __float2bfloat16(O[m][n][i] * inv);
        }
}

// ---------------- resconv (33-tap along seq): out = bf16(oin + conv)
__global__ __launch_bounds__(256) void resconv_tile_k(const __hip_bfloat16* __restrict__ qkvb16,
    const float* __restrict__ rw, const __hip_bfloat16* __restrict__ oin,
    __hip_bfloat16* __restrict__ oout)
{
    int cg = blockIdx.y;
    int t0 = blockIdx.x << 7;
    int tid = threadIdx.x;
    int lane = tid & 63, w = tid >> 6;
    __shared__ float vt[160][64];
    __shared__ float wr[33];
    if (tid < 33) wr[tid] = rw[cg * 33 + tid];
    for (int e = tid; e < 160 * 64; e += 256) {
        int tt = e >> 6, l = e & 63;
        int t = t0 - 16 + tt;
        vt[tt][l] = (t >= 0 && t < NP)
            ? __bfloat162float(qkvb16[(size_t)t * QKVW + 1024 + (cg << 6) + l]) : 0.f;
    }
    __syncthreads();
    for (int i = 0; i < 32; ++i) {
        int tl = (w << 5) + i;
        float acc = 0.f;
#pragma unroll
        for (int ky = 0; ky < 33; ++ky) acc += wr[ky] * vt[tl + ky][lane];
        size_t oi = (size_t)(t0 + tl) * DIMF + (cg << 6) + lane;
        oout[oi] = __float2bfloat16(__bfloat162float(oin[oi]) + acc);
    }
}

// ---------------- PPEG v3: 32 ch/block, float2/thread, conflict-free bf16 LDS
__global__ __launch_bounds__(256) void ppeg3_k(const float* __restrict__ x,
    const float* __restrict__ w7, const float* __restrict__ b7,
    const float* __restrict__ w5, const float* __restrict__ b5,
    const float* __restrict__ w3, const float* __restrict__ b3,
    float* __restrict__ outfeat)
{
    int cg = blockIdx.y;
    int ty0 = (blockIdx.x >> 4) << 3, tx0 = (blockIdx.x & 15) << 3;
    int tid = threadIdx.x;
    int cgi = tid & 15;
    int xo = (tid >> 4) & 7;
    int yb0 = (tid >> 7) << 2;
    int c = (cg << 5) + (cgi << 1);
    const float* feat = x + DIMF;
    __shared__ __align__(16) __hip_bfloat16 tile[196][32];
    __shared__ __align__(16) __hip_bfloat16 ws7[49][32];
    __shared__ __align__(16) __hip_bfloat16 ws5[25][32];
    __shared__ __align__(16) __hip_bfloat16 ws3[9][32];
    for (int e = tid; e < 49 * 32; e += 256) {
        int t = e >> 5, cl = e & 31;
        ws7[t][cl] = __float2bfloat16(w7[(size_t)((cg << 5) + cl) * 49 + t]);
    }
    for (int e = tid; e < 25 * 32; e += 256) {
        int t = e >> 5, cl = e & 31;
        ws5[t][cl] = __float2bfloat16(w5[(size_t)((cg << 5) + cl) * 25 + t]);
    }
    for (int e = tid; e < 9 * 32; e += 256) {
        int t = e >> 5, cl = e & 31;
        ws3[t][cl] = __float2bfloat16(w3[(size_t)((cg << 5) + cl) * 9 + t]);
    }
    for (int e = tid; e < 196 * 16; e += 256) {
        int sp = e >> 4, cp = (e & 15) << 1;
        int yy = ty0 - 3 + sp / 14, xc = tx0 - 3 + sp % 14;
        float2 v = make_float2(0.f, 0.f);
        if ((unsigned)yy < 128u && (unsigned)xc < 128u)
            v = *(const float2*)&feat[(size_t)(yy * 128 + xc) * DIMF + (cg << 5) + cp];
        *(unsigned*)&tile[sp][cp] = f2b16(v.x, v.y);
    }
    __syncthreads();
    float2 bs7 = *(const float2*)&b7[c], bs5 = *(const float2*)&b5[c], bs3 = *(const float2*)&b3[c];
    float bsx = bs7.x + bs5.x + bs3.x, bsy = bs7.y + bs5.y + bs3.y;
    float2 acc[4];
#pragma unroll
    for (int o = 0; o < 4; ++o) {
        float2 idv = *(const float2*)&feat[(size_t)((ty0 + yb0 + o) * 128 + tx0 + xo) * DIMF + c];
        acc[o].x = idv.x + bsx;
        acc[o].y = idv.y + bsy;
    }
    int c2 = cgi << 1;
#pragma unroll
    for (int kx = 0; kx < 7; ++kx) {
        float2 wc[7];
#pragma unroll
        for (int j = 0; j < 7; ++j) wc[j] = b2f(&ws7[j * 7 + kx][c2]);
#pragma unroll
        for (int r = 0; r < 10; ++r) {
            float2 v = b2f(&tile[(yb0 + r) * 14 + xo + kx][c2]);
#pragma unroll
            for (int o = 0; o < 4; ++o) {
                int ky = r - o;
                if (ky >= 0 && ky < 7) {
                    acc[o].x += wc[ky].x * v.x; acc[o].y += wc[ky].y * v.y;
                }
            }
        }
    }
#pragma unroll
    for (int kx = 0; kx < 5; ++kx) {
        float2 wc[5];
#pragma unroll
        for (int j = 0; j < 5; ++j) wc[j] = b2f(&ws5[j * 5 + kx][c2]);
#pragma unroll
        for (int r = 0; r < 8; ++r) {
            float2 v = b2f(&tile[(yb0 + 1 + r) * 14 + xo + 1 + kx][c2]);
#pragma unroll
            for (int o = 0; o < 4; ++o) {
                int ky = r - o;
                if (ky >= 0 && ky < 5) {
                    acc[o].x += wc[ky].x * v.x; acc[o].y += wc[ky].y * v.y;
                }
            }
        }
    }
#pragma unroll
    for (int kx = 0; kx < 3; ++kx) {
        float2 wc[3];
#pragma unroll
        for (int j = 0; j < 3; ++j) wc[j] = b2f(&ws3[j * 3 + kx][c2]);
#pragma unroll
        for (int r = 0; r < 6; ++r) {
            float2 v = b2f(&tile[(yb0 + 2 + r) * 14 + xo + 2 + kx][c2]);
#pragma unroll
            for (int o = 0; o < 4; ++o) {
                int ky = r - o;
                if (ky >= 0 && ky < 3) {
                    acc[o].x += wc[ky].x * v.x; acc[o].y += wc[ky].y * v.y;
                }
            }
        }
    }
#pragma unroll
    for (int o = 0; o < 4; ++o)
        *(float2*)&outfeat[(size_t)((ty0 + yb0 + o) * 128 + tx0 + xo) * DIMF + c] = acc[o];
}

// ---------------- final LN(row0) + 2-class head + softmax + argmax
__global__ __launch_bounds__(64) void head_k(const float* __restrict__ x,
    const float* __restrict__ g, const float* __restrict__ b,
    const float* __restrict__ w, const float* __restrict__ bias, float* __restrict__ out)
{
    int lane = threadIdx.x;
    float v[8], s = 0.f;
#pragma unroll
    for (int i = 0; i < 8; ++i) { v[i] = x[i * 64 + lane]; s += v[i]; }
#pragma unroll
    for (int off = 32; off; off >>= 1) s += __shfl_xor(s, off);
    float mu = s * (1.f / 512.f);
    float vs = 0.f;
#pragma unroll
    for (int i = 0; i < 8; ++i) { float d = v[i] - mu; vs += d * d; }
#pragma unroll
    for (int off = 32; off; off >>= 1) vs += __shfl_xor(vs, off);
    float rstd = rsqrtf(vs * (1.f / 512.f) + 1e-5f);
    float l0 = 0.f, l1 = 0.f;
#pragma unroll
    for (int i = 0; i < 8; ++i) {
        int d = i * 64 + lane;
        float hn = (v[i] - mu) * rstd * g[d] + b[d];
        l0 += hn * w[d * 2];
        l1 += hn * w[d * 2 + 1];
    }
#pragma unroll
    for (int off = 32; off; off >>= 1) { l0 += __shfl_xor(l0, off); l1 += __shfl_xor(l1, off); }
    if (lane == 0) {
        l0 += bias[0]; l1 += bias[1];
        float m = fmaxf(l0, l1);
        float e0 = __expf(l0 - m), e1 = __expf(l1 - m);
        float ss = e0 + e1;
        out[0] = l0; out[1] = l1;
        out[2] = e0 / ss; out[3] = e1 / ss;
        out[4] = (l1 > l0) ? 1.f : 0.f;
    }
}

extern "C" void kernel_launch(void* const* d_in, const int* in_sizes, int n_in,
                              void* d_out, int out_size, void* d_ws, size_t ws_size,
                              hipStream_t stream)
{
    (void)in_sizes; (void)n_in; (void)out_size; (void)ws_size;
    const float* data   = (const float*)d_in[0];
    const float* fc1_w  = (const float*)d_in[1];
    const float* fc1_b  = (const float*)d_in[2];
    const float* cls    = (const float*)d_in[3];
    const float* l1_ng  = (const float*)d_in[4];
    const float* l1_nb  = (const float*)d_in[5];
    const float* l1_qkv = (const float*)d_in[6];
    const float* l1_ow  = (const float*)d_in[7];
    const float* l1_ob  = (const float*)d_in[8];
    const float* l1_rw  = (const float*)d_in[9];
    const float* l2_ng  = (const float*)d_in[10];
    const float* l2_nb  = (const float*)d_in[11];
    const float* l2_qkv = (const float*)d_in[12];
    const float* l2_ow  = (const float*)d_in[13];
    const float* l2_ob  = (const float*)d_in[14];
    const float* l2_rw  = (const float*)d_in[15];
    const float* p_w7   = (const float*)d_in[16];
    const float* p_b7   = (const float*)d_in[17];
    const float* p_w5   = (const float*)d_in[18];
    const float* p_b5   = (const float*)d_in[19];
    const float* p_w3   = (const float*)d_in[20];
    const float* p_b3   = (const float*)d_in[21];
    const float* n_g    = (const float*)d_in[22];
    const float* n_b    = (const float*)d_in[23];
    const float* fc2_w  = (const float*)d_in[24];
    const float* fc2_b  = (const float*)d_in[25];

    char* base = (char*)d_ws;
    auto carve = [&](size_t bytes) { char* p = base; base += (bytes + 255) & ~(size_t)255; return p; };
    float* x               = (float*)carve((size_t)NT * DIMF * 4);
    float* x2              = (float*)carve((size_t)NT * DIMF * 4);
    __hip_bfloat16* xp16   = (__hip_bfloat16*)carve((size_t)NP * DIMF * 2);   // alias: obuf2
    __hip_bfloat16* qkvb16 = (__hip_bfloat16*)carve((size_t)NP * QKVW * 2);   // alias: data16
    __hip_bfloat16* vT16   = (__hip_bfloat16*)carve((size_t)NHEAD * DH * NP * 2);
    __hip_bfloat16* obuf16 = (__hip_bfloat16*)carve((size_t)NP * DIMF * 2);
    __hip_bfloat16* wT     = (__hip_bfloat16*)carve((size_t)QKVW * DIMF * 2);
    float* ql              = (float*)carve(131072 * 4);
    float* kl              = (float*)carve(131072 * 4);
    __hip_bfloat16* ql16   = (__hip_bfloat16*)carve(131072 * 2);
    __hip_bfloat16* kl16   = (__hip_bfloat16*)carve(131072 * 2);
    __hip_bfloat16* wmT16  = (__hip_bfloat16*)carve(131072 * 2);
    float* a2              = (float*)carve(524288 * 4);
    __hip_bfloat16* a2_16  = (__hip_bfloat16*)carve(524288 * 2);
    __hip_bfloat16* zrA    = (__hip_bfloat16*)carve(524288 * 2);
    __hip_bfloat16* zrB    = (__hip_bfloat16*)carve(524288 * 2);
    __hip_bfloat16* ztA    = (__hip_bfloat16*)carve(524288 * 2);
    __hip_bfloat16* ztB    = (__hip_bfloat16*)carve(524288 * 2);
    __hip_bfloat16* xz16   = (__hip_bfloat16*)carve(524288 * 2);
    __hip_bfloat16* t1T16  = (__hip_bfloat16*)carve(524288 * 2);
    __hip_bfloat16* a3vT16 = (__hip_bfloat16*)carve(131072 * 2);
    float* opart = (float*)carve((size_t)64 * A3V_TC * 2048 * 4);
    float* mpart = (float*)carve((size_t)64 * A3V_TC * 32 * 4);
    float* lpart = (float*)carve((size_t)64 * A3V_TC * 32 * 4);
    __hip_bfloat16* obuf2  = xp16;
    __hip_bfloat16* data16 = qkvb16;

    // ---- stem
    cvt_k<<<(16384 * 1024 / 4 + 255) / 256, 256, 0, stream>>>(
        (const float4*)data, (ushort4*)data16, 16384 * 1024 / 4);
    transcvt_k<<<(DIMF / 32) * (1024 / 32), 256, 0, stream>>>(fc1_w, wT, 1024, DIMF);
    gemm_bf16_k<<<dim3(DIMF / 128, 16384 / 128), 256, 0, stream>>>(
        data16, wT, fc1_b, nullptr, x + DIMF, nullptr, 16384, DIMF, 1024, 16384, 1);
    hipMemcpyAsync(x, cls, DIMF * sizeof(float), hipMemcpyDeviceToDevice, stream);

    auto layer = [&](float* xv, const float* ng, const float* nb, const float* qw,
                     const float* ow, const float* ob, const float* rw) {
        ln_k<<<NP, 64, 0, stream>>>(xv, ng, nb, xp16);
        transcvt_k<<<(QKVW / 32) * (DIMF / 32), 256, 0, stream>>>(qw, wT, DIMF, QKVW);
        gemm_bf16_k<<<dim3(QKVW / 128, NP / 128), 256, 0, stream>>>(
            xp16, wT, nullptr, nullptr, nullptr, qkvb16, NP, QKVW, DIMF, NP, 0);
        vtrans_k<<<dim3(NP / 64, NHEAD), 256, 0, stream>>>(qkvb16, vT16);
        landmark_k<<<NHEAD * NLM, 256, 0, stream>>>(qkvb16, ql, kl, ql16, kl16);
        a2_k<<<NHEAD * NLM, 256, 0, stream>>>(ql, kl, a2, a2_16);
        zinit_k<<<NHEAD, 256, 0, stream>>>(a2, zrA, ztA);
        __hip_bfloat16 *zr = zrA, *zt = ztA, *zrN = zrB, *ztN = ztB;
        for (int it = 0; it < 6; ++it) {
            pgemm1_k<<<dim3(4, NHEAD), 256, 0, stream>>>(a2_16, zt, xz16, t1T16);
            pgemm3_k<<<dim3(4, NHEAD), 256, 0, stream>>>(xz16, t1T16, zr, zrN, ztN);
            __hip_bfloat16* t;
            t = zr; zr = zrN; zrN = t;
            t = zt; zt = ztN; ztN = t;
        }
        a3v_flash_k<<<dim3(32, A3V_TC), 128, 0, stream>>>(ql16, qkvb16, vT16, opart, mpart, lpart);
        a3v_comb_k<<<64, 64, 0, stream>>>(opart, mpart, lpart, a3vT16);
        wm_k<<<NHEAD, 256, 0, stream>>>(zr, a3vT16, wmT16);
        attnout_mfma_k<<<dim3(NP / 64, NHEAD), 128, 0, stream>>>(qkvb16, kl16, wmT16, obuf16);
        resconv_tile_k<<<dim3(NP / 128, NHEAD), 256, 0, stream>>>(qkvb16, rw, obuf16, obuf2);
        transcvt_k<<<(DIMF / 32) * (DIMF / 32), 256, 0, stream>>>(ow, wT, DIMF, DIMF);
        gemm_bf16_k<<<dim3(DIMF / 128, (NT + 127) / 128), 256, 0, stream>>>(
            obuf2 + (size_t)PADR * DIMF, wT, ob, xv, xv, nullptr, NT, DIMF, DIMF, NT, 0);
    };

    layer(x, l1_ng, l1_nb, l1_qkv, l1_ow, l1_ob, l1_rw);

    ppeg3_k<<<dim3(256, 16), 256, 0, stream>>>(x, p_w7, p_b7, p_w5, p_b5, p_w3, p_b3, x2 + DIMF);
    hipMemcpyAsync(x2, x, DIMF * sizeof(float), hipMemcpyDeviceToDevice, stream);

    layer(x2, l2_ng, l2_nb, l2_qkv, l2_ow, l2_ob, l2_rw);

    head_k<<<1, 64, 0, stream>>>(x2, n_g, n_b, fc2_w, fc2_b, (float*)d_out);
}